// Round 16
// baseline (444.402 us; speedup 1.0000x reference)
//
#include <hip/hip_runtime.h>
#include <hip/hip_bf16.h>

#define H 768
#define NTOT 192
#define A4W 3072
#define GW 2304

typedef __attribute__((ext_vector_type(4))) float f32x4;
typedef __attribute__((ext_vector_type(8))) unsigned short u16x8;
typedef __attribute__((ext_vector_type(4))) unsigned short u16x4;
typedef __attribute__((ext_vector_type(8))) __bf16 bf16x8v;

static __device__ __forceinline__ unsigned short f2bf(float f) {
  __hip_bfloat16 b = __float2bfloat16(f);
  return __builtin_bit_cast(unsigned short, b);
}
static __device__ __forceinline__ float bf2f(unsigned short u) {
  return __bfloat162float(__builtin_bit_cast(__hip_bfloat16, u));
}
static __device__ __forceinline__ f32x4 MFMA(u16x8 a, u16x8 b, f32x4 c) {
  return __builtin_amdgcn_mfma_f32_16x16x32_bf16(
      __builtin_bit_cast(bf16x8v, a), __builtin_bit_cast(bf16x8v, b), c, 0, 0, 0);
}
static __device__ __forceinline__ u16x8 ld8(const unsigned short* p) {
  return *(const u16x8*)p;
}
static __device__ __forceinline__ unsigned int cvtpk(float lo, float hi) {
  unsigned int r;
  asm("v_cvt_pk_bf16_f32 %0, %1, %2" : "=v"(r) : "v"(lo), "v"(hi));
  return r;
}
static __device__ __forceinline__ float relu(float x) { return fmaxf(x, 0.f); }

#define GLDS16(gp, lp)                                                   \
  __builtin_amdgcn_global_load_lds(                                      \
      (const __attribute__((address_space(1))) void*)(gp),               \
      (__attribute__((address_space(3))) void*)(lp), 16, 0, 0)

// ---------------- fused prep: weight conversions + bc + inith --------------
__global__ void k_prep(const float* __restrict__ Wm1, const float* __restrict__ W2s,
                       const float* __restrict__ W2d, const float* __restrict__ Whh,
                       const float* __restrict__ Wih, const float* __restrict__ Wm2,
                       const float* __restrict__ W1s, const float* __restrict__ W1d,
                       const float* __restrict__ b1s, const float* __restrict__ b1d,
                       const float* __restrict__ bm2, const float* __restrict__ bih,
                       const float* __restrict__ asp, const float* __restrict__ qry,
                       unsigned short* __restrict__ Wm1bf, unsigned short* __restrict__ W2sbf,
                       unsigned short* __restrict__ W2dbf, unsigned short* __restrict__ Whhh,
                       unsigned short* __restrict__ Whhl, unsigned short* __restrict__ Wm2th,
                       unsigned short* __restrict__ Wm2tl, unsigned short* __restrict__ W1cat,
                       float* __restrict__ b1cat, float* __restrict__ bc,
                       float* __restrict__ h, unsigned short* __restrict__ hhi,
                       unsigned short* __restrict__ hlo) {
  const int b = blockIdx.x, tid = threadIdx.x;
  if (b < 576) {
    int u = b * 256 + tid;
    float4 v = ((const float4*)Wm1)[u];
    u16x4 o; o[0] = f2bf(v.x); o[1] = f2bf(v.y); o[2] = f2bf(v.z); o[3] = f2bf(v.w);
    ((u16x4*)Wm1bf)[u] = o;
  } else if (b < 588) {
    int u = (b - 576) * 256 + tid;
    float4 v = ((const float4*)W2s)[u];
    u16x4 o; o[0] = f2bf(v.x); o[1] = f2bf(v.y); o[2] = f2bf(v.z); o[3] = f2bf(v.w);
    ((u16x4*)W2sbf)[u] = o;
  } else if (b < 600) {
    int u = (b - 588) * 256 + tid;
    float4 v = ((const float4*)W2d)[u];
    u16x4 o; o[0] = f2bf(v.x); o[1] = f2bf(v.y); o[2] = f2bf(v.z); o[3] = f2bf(v.w);
    ((u16x4*)W2dbf)[u] = o;
  } else if (b < 2328) {
    int u = (b - 600) * 256 + tid;
    float4 v = ((const float4*)Whh)[u];
    u16x4 oh, ol;
#pragma unroll
    for (int j = 0; j < 4; ++j) {
      float f = ((const float*)&v)[j];
      oh[j] = f2bf(f); ol[j] = f2bf(f - bf2f(oh[j]));
    }
    ((u16x4*)Whhh)[u] = oh; ((u16x4*)Whhl)[u] = ol;
  } else if (b < 2904) {
    int u = (b - 2328) * 256 + tid;  // Wm2 f4 index; emit TRANSPOSED hi/lo
    float4 v = ((const float4*)Wm2)[u];
    int e_lin = u * 4;
    int er = e_lin / H, kc = e_lin - er * H;
#pragma unroll
    for (int j = 0; j < 4; ++j) {
      float f = ((const float*)&v)[j];
      unsigned short hi = f2bf(f);
      Wm2th[(size_t)(kc + j) * H + er] = hi;
      Wm2tl[(size_t)(kc + j) * H + er] = f2bf(f - bf2f(hi));
    }
  } else if (b < 5208) {
    int u = (b - 2904) * 256 + tid;  // f4 index into W1cat [3072][768]
    int e = u * 4;
    int row = e / H, k = e - row * H;
    int part = row / H, o = row - part * H;
    const float* W = (part < 2) ? W1s : W1d;
    float4 v = *(const float4*)(W + (size_t)o * (2 * H) + (part & 1) * H + k);
    u16x4 ov; ov[0] = f2bf(v.x); ov[1] = f2bf(v.y); ov[2] = f2bf(v.z); ov[3] = f2bf(v.w);
    *(u16x4*)(W1cat + e) = ov;
    if (u < 768) {
      int e2 = u * 4, pp = e2 / H, oo = e2 - pp * H;
      float4 bv;
      if (pp == 0) bv = *(const float4*)(b1s + oo);
      else if (pp == 2) bv = *(const float4*)(b1d + oo);
      else bv = (float4){0.f, 0.f, 0.f, 0.f};
      *(float4*)(b1cat + e2) = bv;
    }
  } else if (b < 5784) {
    const int w = tid >> 6, l = tid & 63;
    const int gg = (b - 5208) * 4 + w;
    const float* row = Wih + (size_t)gg * H;
    float s = 0.f;
#pragma unroll
    for (int q = 0; q < 12; ++q) s += row[l + q * 64] * bm2[l + q * 64];
#pragma unroll
    for (int m = 32; m; m >>= 1) s += __shfl_xor(s, m);
    if (l == 0) bc[gg] = bih[gg] + s;
  } else {
    int u = (b - 5784) * 256 + tid;  // f4 index, 36864
    float4 v = (u < 12288) ? ((const float4*)asp)[u] : ((const float4*)qry)[u - 12288];
    ((float4*)h)[u] = v;
    u16x4 oh, ol;
#pragma unroll
    for (int j = 0; j < 4; ++j) {
      float f = ((const float*)&v)[j];
      oh[j] = f2bf(f); ol[j] = f2bf(f - bf2f(oh[j]));
    }
    ((u16x4*)hhi)[u] = oh; ((u16x4*)hlo)[u] = ol;
  }
}

// ---------------- merged prep GEMM, 48 KB LDS, 1584 blocks ------------------
// INTERLEAVED dispatch: wg%11<8 -> RsW block (1152 total), else Wc (432 total)
// so Wc co-schedules with RsW instead of forming a serial tail.
// RsW: round-11 proven form (A dbuf, early issue, sched_barrier pin).
__global__ __launch_bounds__(256) void k_pre2(const unsigned short* __restrict__ Wm1bf,
                                              const float* __restrict__ Rsf,
                                              const float* __restrict__ Rdf,
                                              unsigned short* __restrict__ RsWt,
                                              const float* __restrict__ Wih,
                                              const unsigned short* __restrict__ Bth,
                                              const unsigned short* __restrict__ Btl,
                                              unsigned short* __restrict__ Ch,
                                              unsigned short* __restrict__ Cl) {
  __shared__ unsigned short LDS[24576];  // 48 KB
  const int wg = blockIdx.x;             // 1584 = 11 * 144
  const int grp = wg / 11, lane11 = wg % 11;
  const int tid = threadIdx.x, w = tid >> 6, l = tid & 63;
  const int g = l >> 4, ln = l & 15;
  const int srow = l >> 3;
  const int skb = ((l & 7) ^ srow) * 8;
  const int x7 = ln & 7;

  if (lane11 >= 8) {
    // --------- Wc: 64x64 tile, BK=64 ---------------------------------------
    unsigned short* Ahl = LDS;
    unsigned short* All = LDS + 4096;
    unsigned short* Bhl = LDS + 8192;
    unsigned short* Bll = LDS + 12288;
    const int bid = grp * 3 + (lane11 - 8);        // 0..431
    const int m0 = (bid / 12) * 64, n0 = (bid % 12) * 64;
    const unsigned short* Bgh = Bth + (size_t)(n0 + srow) * H + skb;
    const unsigned short* Bgl = Btl + (size_t)(n0 + srow) * H + skb;
    f32x4 acc[4];
#pragma unroll
    for (int mi = 0; mi < 4; ++mi) acc[mi] = (f32x4){0.f, 0.f, 0.f, 0.f};
    for (int kb = 0; kb < H; kb += 64) {
#pragma unroll
      for (int c2 = 0; c2 < 2; ++c2) {
        const int c = w * 2 + c2;
        GLDS16(Bgh + (size_t)(c * 8) * H + kb, &Bhl[c * 512]);
        GLDS16(Bgl + (size_t)(c * 8) * H + kb, &Bll[c * 512]);
      }
#pragma unroll
      for (int q = 0; q < 2; ++q) {
        const int idx = q * 256 + tid;
        const int row = idx >> 3, kb8 = idx & 7;
        const float* src = Wih + (size_t)(m0 + row) * H + kb + kb8 * 8;
        float4 v0 = *(const float4*)src;
        float4 v1 = *(const float4*)(src + 4);
        float fv[8] = {v0.x, v0.y, v0.z, v0.w, v1.x, v1.y, v1.z, v1.w};
        u16x8 oh, ol;
#pragma unroll
        for (int jq = 0; jq < 8; ++jq) {
          unsigned short hi = f2bf(fv[jq]);
          oh[jq] = hi;
          ol[jq] = f2bf(fv[jq] - bf2f(hi));
        }
        const int dst = row * 64 + (kb8 ^ (row & 7)) * 8;
        *(u16x8*)&Ahl[dst] = oh;
        *(u16x8*)&All[dst] = ol;
      }
      __syncthreads();
#pragma unroll
      for (int kk = 0; kk < 2; ++kk) {
        const int pb = ((kk * 4 + g) ^ x7) * 8;
        u16x8 bh = ld8(&Bhl[(w * 16 + ln) * 64 + pb]);
        u16x8 bl = ld8(&Bll[(w * 16 + ln) * 64 + pb]);
#pragma unroll
        for (int mi = 0; mi < 4; ++mi) {
          u16x8 ah = ld8(&Ahl[(mi * 16 + ln) * 64 + pb]);
          u16x8 al = ld8(&All[(mi * 16 + ln) * 64 + pb]);
          acc[mi] = MFMA(ah, bh, acc[mi]);
          acc[mi] = MFMA(ah, bl, acc[mi]);
          acc[mi] = MFMA(al, bh, acc[mi]);
        }
      }
      __syncthreads();
    }
#pragma unroll
    for (int mi = 0; mi < 4; ++mi) {
      const int col = n0 + w * 16 + ln;
#pragma unroll
      for (int pp = 0; pp < 4; ++pp) {
        const int row = m0 + mi * 16 + g * 4 + pp;
        const float val = acc[mi][pp];
        unsigned short hi = f2bf(val);
        Ch[(size_t)row * H + col] = hi;
        Cl[(size_t)row * H + col] = f2bf(val - bf2f(hi));
      }
    }
    return;
  }

  // --------- RsW: round-11 proven form -------------------------------------
  unsigned short* Asl0 = LDS;           // 16 KB
  unsigned short* Asl1 = LDS + 8192;    // 16 KB (A double buffer)
  unsigned short* Bsl = LDS + 16384;    // 16 KB
  const int rid = grp * 8 + lane11;                // 0..1151
  const int nb = (rid & 7) * 144 + (rid >> 3);     // chunked XCD swizzle
  const int z = nb / 36, t5 = nb - z * 36;
  const int d0 = (t5 / 6) * 128, k0 = (t5 % 6) * 128;
  const int wr = w >> 1, wc = w & 1;
  const unsigned short* Ag = Wm1bf + (size_t)(d0 + srow) * H + skb;
  const float* Bg = ((z < 16) ? Rsf : Rdf) + (size_t)(z & 15) * (H * H);
  const int kb8 = tid & 7, rb = tid >> 3;
  const float* Bq = Bg + (size_t)(k0 + rb) * H + kb8 * 8;
  const int bdst = rb * 64 + (kb8 ^ (rb & 7)) * 8;

#define LOADB_(kbv, Ra, Rb)                                  \
  _Pragma("unroll") for (int q = 0; q < 4; ++q) {            \
    const float* s_ = Bq + (size_t)(q * 32) * H + (kbv);     \
    Ra[q] = *(const float4*)s_;                              \
    Rb[q] = *(const float4*)(s_ + 4);                        \
  }
#define WRITEB_(Ra, Rb)                                      \
  _Pragma("unroll") for (int q = 0; q < 4; ++q) {            \
    u16x8 o_; unsigned int* po_ = (unsigned int*)&o_;        \
    po_[0] = cvtpk(Ra[q].x, Ra[q].y);                        \
    po_[1] = cvtpk(Ra[q].z, Ra[q].w);                        \
    po_[2] = cvtpk(Rb[q].x, Rb[q].y);                        \
    po_[3] = cvtpk(Rb[q].z, Rb[q].w);                        \
    *(u16x8*)&Bsl[q * 2048 + bdst] = o_;                     \
  }
#define GLDSA_(kbv, buf)                                     \
  _Pragma("unroll") for (int c4 = 0; c4 < 4; ++c4) {         \
    const int c_ = w * 4 + c4;                               \
    GLDS16(Ag + (size_t)(c_ * 8) * H + (kbv), &(buf)[c_ * 512]); \
  }

  f32x4 acc[4][4];
#pragma unroll
  for (int mi = 0; mi < 4; ++mi)
#pragma unroll
    for (int ni = 0; ni < 4; ++ni) acc[mi][ni] = (f32x4){0.f, 0.f, 0.f, 0.f};
  float4 ra[4], rbv[4];
  GLDSA_(0, Asl0);
  LOADB_(0, ra, rbv);
  WRITEB_(ra, rbv);
  __syncthreads();
#pragma unroll
  for (int t = 0; t < 12; ++t) {
    unsigned short* Acur = (t & 1) ? Asl1 : Asl0;
    unsigned short* Anxt = (t & 1) ? Asl0 : Asl1;
    if (t < 11) {
      GLDSA_((t + 1) * 64, Anxt);
      LOADB_((t + 1) * 64, ra, rbv);
    }
    __builtin_amdgcn_sched_barrier(0);
#pragma unroll
    for (int kk = 0; kk < 2; ++kk) {
      u16x8 af[4], bf[4];
      const int pb = ((kk * 4 + g) ^ x7) * 8;
#pragma unroll
      for (int mi = 0; mi < 4; ++mi) af[mi] = ld8(&Acur[(wr * 64 + mi * 16 + ln) * 64 + pb]);
#pragma unroll
      for (int ni = 0; ni < 4; ++ni) bf[ni] = ld8(&Bsl[(wc * 64 + ni * 16 + ln) * 64 + pb]);
#pragma unroll
      for (int mi = 0; mi < 4; ++mi)
#pragma unroll
        for (int ni = 0; ni < 4; ++ni) acc[mi][ni] = MFMA(af[mi], bf[ni], acc[mi][ni]);
    }
    __syncthreads();
    if (t < 11) {
      WRITEB_(ra, rbv);
      __syncthreads();
    }
  }
#pragma unroll
  for (int mi = 0; mi < 4; ++mi) {
    const int d = d0 + wr * 64 + mi * 16 + g * 4;
#pragma unroll
    for (int ni = 0; ni < 4; ++ni) {
      const int k = k0 + wc * 64 + ni * 16 + ln;
      unsigned short* o = RsWt + ((size_t)d * 32 + z) * H + k;
#pragma unroll
      for (int pp = 0; pp < 4; ++pp) o[(size_t)pp * 32 * H] = f2bf(acc[mi][ni][pp]);
    }
  }
#undef LOADB_
#undef WRITEB_
#undef GLDSA_
}

// ---------------- K-split(4) hilo GEMM for gx (no bias, raw partials) -------
__global__ __launch_bounds__(256) void k_btks(
    const unsigned short* __restrict__ Ahi, const unsigned short* __restrict__ Alo,
    const unsigned short* __restrict__ Bhi, const unsigned short* __restrict__ Blo,
    float* __restrict__ Cp) {
  const int tid = threadIdx.x;
  const int w = tid >> 6, l = tid & 63, g = l >> 4, ln = l & 15;
  const int m0 = blockIdx.y * 64 + w * 16;
  const int n0 = blockIdx.x * 64;
  const int kh = blockIdx.z, kb0 = kh * 192;
  const unsigned short* aph = Ahi + (size_t)(m0 + ln) * H + kb0 + g * 8;
  const unsigned short* apl = Alo + (size_t)(m0 + ln) * H + kb0 + g * 8;
  const unsigned short* bph[4];
  const unsigned short* bpl[4];
#pragma unroll
  for (int nt = 0; nt < 4; ++nt) {
    bph[nt] = Bhi + (size_t)(n0 + nt * 16 + ln) * H + kb0 + g * 8;
    bpl[nt] = Blo + (size_t)(n0 + nt * 16 + ln) * H + kb0 + g * 8;
  }
  f32x4 acc[4];
#pragma unroll
  for (int nt = 0; nt < 4; ++nt) acc[nt] = (f32x4){0.f, 0.f, 0.f, 0.f};
  u16x8 ah[2], al[2], bh[2][4], bl[2][4];
  ah[0] = ld8(aph);
  al[0] = ld8(apl);
#pragma unroll
  for (int nt = 0; nt < 4; ++nt) { bh[0][nt] = ld8(bph[nt]); bl[0][nt] = ld8(bpl[nt]); }
#pragma unroll
  for (int t = 0; t < 6; ++t) {
    const int cur = t & 1, nxt = cur ^ 1;
    if (t < 5) {
      const int ko = (t + 1) * 32;
      ah[nxt] = ld8(aph + ko);
      al[nxt] = ld8(apl + ko);
#pragma unroll
      for (int nt = 0; nt < 4; ++nt) {
        bh[nxt][nt] = ld8(bph[nt] + ko);
        bl[nxt][nt] = ld8(bpl[nt] + ko);
      }
    }
#pragma unroll
    for (int nt = 0; nt < 4; ++nt) {
      acc[nt] = MFMA(ah[cur], bh[cur][nt], acc[nt]);
      acc[nt] = MFMA(ah[cur], bl[cur][nt], acc[nt]);
      acc[nt] = MFMA(al[cur], bh[cur][nt], acc[nt]);
    }
  }
#pragma unroll
  for (int nt = 0; nt < 4; ++nt) {
    const int col = n0 + nt * 16 + ln;
#pragma unroll
    for (int pp = 0; pp < 4; ++pp) {
      const int row = m0 + g * 4 + pp;
      Cp[(size_t)kh * (NTOT * GW) + (size_t)row * GW + col] = acc[nt][pp];
    }
  }
}

// ---------------- per-step LDS-staged tiled GEMM: gh | A4 | twB -------------
// 64(M) x 128(N) tiles, BK=64. Bijective XCD swizzle.
// Paths 1/2: A+B double-buffered, early issue. Path 0 (gh, hilo): original.
__global__ __launch_bounds__(256) void k_tile(
    const unsigned short* __restrict__ hhi, const unsigned short* __restrict__ hlo,
    const unsigned short* __restrict__ W1cat, const float* __restrict__ b1cat,
    const unsigned short* __restrict__ Whhh, const unsigned short* __restrict__ Whhl,
    const float* __restrict__ bhh, const unsigned short* __restrict__ RsWt,
    float* __restrict__ A4, float* __restrict__ ghb, unsigned short* __restrict__ twB) {
  __shared__ unsigned short LDS[24576];  // 48 KB
  const int orig = blockIdx.x;           // 702 blocks
  const int qq = 87, rr = 6;             // 702 = 8*87 + 6
  const int xcd = orig & 7, idx = orig >> 3;
  const int bid = (xcd < rr ? xcd * (qq + 1) : rr * (qq + 1) + (xcd - rr) * qq) + idx;
  const int tid = threadIdx.x, w = tid >> 6, l = tid & 63, g = l >> 4, ln = l & 15;
  int path, m, n;
  if (bid < 54)       { path = 0; n = bid / 3;         m = bid % 3; }
  else if (bid < 126) { path = 1; n = (bid - 54) / 3;  m = (bid - 54) % 3; }
  else                { path = 2; n = (bid - 126) / 3; m = (bid - 126) % 3; }
  const int m0 = m * 64, n0 = n * 128;
  const int srow = l >> 3;
  const int skb = ((l & 7) ^ srow) * 8;
  const int x7 = ln & 7;
  f32x4 acc[4][2];
#pragma unroll
  for (int mi = 0; mi < 4; ++mi)
#pragma unroll
    for (int ni = 0; ni < 2; ++ni) acc[mi][ni] = (f32x4){0.f, 0.f, 0.f, 0.f};

  if (path == 0) {
    unsigned short* Ah = LDS;
    unsigned short* Al = LDS + 4096;
    unsigned short* Bh = LDS + 8192;
    unsigned short* Bl = LDS + 16384;
    const unsigned short* Agh = hhi + (size_t)(m0 + srow) * H + skb;
    const unsigned short* Agl = hlo + (size_t)(m0 + srow) * H + skb;
    const unsigned short* Bgh = Whhh + (size_t)(n0 + srow) * H + skb;
    const unsigned short* Bgl = Whhl + (size_t)(n0 + srow) * H + skb;
    for (int kb = 0; kb < H; kb += 64) {
#pragma unroll
      for (int c2 = 0; c2 < 2; ++c2) {
        const int c = w * 2 + c2;
        GLDS16(Agh + (size_t)(c * 8) * H + kb, &Ah[c * 512]);
        GLDS16(Agl + (size_t)(c * 8) * H + kb, &Al[c * 512]);
      }
#pragma unroll
      for (int c4 = 0; c4 < 4; ++c4) {
        const int c = w * 4 + c4;
        GLDS16(Bgh + (size_t)(c * 8) * H + kb, &Bh[c * 512]);
        GLDS16(Bgl + (size_t)(c * 8) * H + kb, &Bl[c * 512]);
      }
      __syncthreads();
#pragma unroll
      for (int kk = 0; kk < 2; ++kk) {
        const int pb = ((kk * 4 + g) ^ x7) * 8;
        u16x8 af[4], bf[2], alf[4], blf[2];
#pragma unroll
        for (int mi = 0; mi < 4; ++mi) {
          af[mi] = ld8(&Ah[(mi * 16 + ln) * 64 + pb]);
          alf[mi] = ld8(&Al[(mi * 16 + ln) * 64 + pb]);
        }
#pragma unroll
        for (int ni = 0; ni < 2; ++ni) {
          bf[ni] = ld8(&Bh[(w * 32 + ni * 16 + ln) * 64 + pb]);
          blf[ni] = ld8(&Bl[(w * 32 + ni * 16 + ln) * 64 + pb]);
        }
#pragma unroll
        for (int mi = 0; mi < 4; ++mi)
#pragma unroll
          for (int ni = 0; ni < 2; ++ni) {
            acc[mi][ni] = MFMA(af[mi], bf[ni], acc[mi][ni]);
            acc[mi][ni] = MFMA(af[mi], blf[ni], acc[mi][ni]);
            acc[mi][ni] = MFMA(alf[mi], bf[ni], acc[mi][ni]);
          }
      }
      __syncthreads();
    }
#pragma unroll
    for (int mi = 0; mi < 4; ++mi)
#pragma unroll
      for (int ni = 0; ni < 2; ++ni) {
        const int col = n0 + w * 32 + ni * 16 + ln;
        const float bv = bhh[col];
#pragma unroll
        for (int pp = 0; pp < 4; ++pp) {
          const int row = m0 + mi * 16 + g * 4 + pp;
          ghb[(size_t)row * GW + col] = acc[mi][ni][pp] + bv;
        }
      }
    return;
  }

  unsigned short* As0 = LDS;            // 8 KB (64x64)
  unsigned short* As1 = LDS + 4096;
  unsigned short* Bs0 = LDS + 8192;     // 16 KB (128x64)
  unsigned short* Bs1 = LDS + 16384;
  const unsigned short* Bsrc = (path == 1) ? W1cat : RsWt;
  const unsigned short* Agh = hhi + (size_t)(m0 + srow) * H + skb;
  const unsigned short* Bgh = Bsrc + (size_t)(n0 + srow) * H + skb;

#define GLDSA2_(kbv, buf)                                    \
  _Pragma("unroll") for (int c2 = 0; c2 < 2; ++c2) {         \
    const int c_ = w * 2 + c2;                               \
    GLDS16(Agh + (size_t)(c_ * 8) * H + (kbv), &(buf)[c_ * 512]); \
  }
#define GLDSB2_(kbv, buf)                                    \
  _Pragma("unroll") for (int c4 = 0; c4 < 4; ++c4) {         \
    const int c_ = w * 4 + c4;                               \
    GLDS16(Bgh + (size_t)(c_ * 8) * H + (kbv), &(buf)[c_ * 512]); \
  }

  GLDSA2_(0, As0);
  GLDSB2_(0, Bs0);
  __syncthreads();
#pragma unroll
  for (int t = 0; t < 12; ++t) {
    unsigned short* Acur = (t & 1) ? As1 : As0;
    unsigned short* Bcur = (t & 1) ? Bs1 : Bs0;
    unsigned short* Anxt = (t & 1) ? As0 : As1;
    unsigned short* Bnxt = (t & 1) ? Bs0 : Bs1;
    if (t < 11) {
      GLDSA2_((t + 1) * 64, Anxt);
      GLDSB2_((t + 1) * 64, Bnxt);
    }
    __builtin_amdgcn_sched_barrier(0);
#pragma unroll
    for (int kk = 0; kk < 2; ++kk) {
      const int pb = ((kk * 4 + g) ^ x7) * 8;
      u16x8 af[4], bf[2];
#pragma unroll
      for (int mi = 0; mi < 4; ++mi) af[mi] = ld8(&Acur[(mi * 16 + ln) * 64 + pb]);
#pragma unroll
      for (int ni = 0; ni < 2; ++ni) bf[ni] = ld8(&Bcur[(w * 32 + ni * 16 + ln) * 64 + pb]);
#pragma unroll
      for (int mi = 0; mi < 4; ++mi)
#pragma unroll
        for (int ni = 0; ni < 2; ++ni) acc[mi][ni] = MFMA(af[mi], bf[ni], acc[mi][ni]);
    }
    __syncthreads();
  }
#undef GLDSA2_
#undef GLDSB2_

  if (path == 2) {
#pragma unroll
    for (int mi = 0; mi < 4; ++mi)
#pragma unroll
      for (int ni = 0; ni < 2; ++ni) {
        const int c = n0 + w * 32 + ni * 16 + ln;
#pragma unroll
        for (int pp = 0; pp < 4; ++pp) {
          const int j = m0 + mi * 16 + g * 4 + pp;
          twB[(size_t)j * 24576 + c] = f2bf(acc[mi][ni][pp]);
        }
      }
  } else {
#pragma unroll
    for (int mi = 0; mi < 4; ++mi)
#pragma unroll
      for (int ni = 0; ni < 2; ++ni) {
        const int col = n0 + w * 32 + ni * 16 + ln;
        const float bv = b1cat[col];
#pragma unroll
        for (int pp = 0; pp < 4; ++pp) {
          const int row = m0 + mi * 16 + g * 4 + pp;
          A4[(size_t)row * A4W + col] = acc[mi][ni][pp] + bv;
        }
      }
  }
}

// ---------------- pair logits + softmax -> swA[j][i][32] (bf16) -------------
__global__ __launch_bounds__(256) void k_pairlog(
    const float* __restrict__ A4, const unsigned short* __restrict__ W2sbf,
    const unsigned short* __restrict__ W2dbf, const float* __restrict__ b2s,
    const float* __restrict__ b2d, unsigned short* __restrict__ swA) {
  __shared__ float red[8][16][17];
  const int i = blockIdx.x, jb = blockIdx.y;
  const int tid = threadIdx.x, w = tid >> 6, l = tid & 63;
  const int g = l >> 4, ln = l & 15;
  const int j = jb * 16 + ln;
  const float* BsP = A4 + (size_t)j * A4W + 768 + g * 8;
  const float* BdP = A4 + (size_t)j * A4W + 2304 + g * 8;
  const float* AsP = A4 + (size_t)i * A4W + g * 8;
  const float* AdP = A4 + (size_t)i * A4W + 1536 + g * 8;
  const unsigned short* WsP = W2sbf + (size_t)ln * H + g * 8;
  const unsigned short* WdP = W2dbf + (size_t)ln * H + g * 8;
  f32x4 accs = (f32x4){0.f, 0.f, 0.f, 0.f}, accd = (f32x4){0.f, 0.f, 0.f, 0.f};
#pragma unroll
  for (int tt = 0; tt < 6; ++tt) {
    const int ko = (w * 6 + tt) * 32;
    float4 b0 = *(const float4*)(BsP + ko), b1 = *(const float4*)(BsP + ko + 4);
    float4 a0 = *(const float4*)(AsP + ko), a1 = *(const float4*)(AsP + ko + 4);
    float4 e0 = *(const float4*)(BdP + ko), e1 = *(const float4*)(BdP + ko + 4);
    float4 c0 = *(const float4*)(AdP + ko), c1 = *(const float4*)(AdP + ko + 4);
    u16x8 afs, afd;
    unsigned int* ps = (unsigned int*)&afs;
    ps[0] = cvtpk(relu(a0.x + b0.x), relu(a0.y + b0.y));
    ps[1] = cvtpk(relu(a0.z + b0.z), relu(a0.w + b0.w));
    ps[2] = cvtpk(relu(a1.x + b1.x), relu(a1.y + b1.y));
    ps[3] = cvtpk(relu(a1.z + b1.z), relu(a1.w + b1.w));
    unsigned int* pd = (unsigned int*)&afd;
    pd[0] = cvtpk(relu(c0.x + e0.x), relu(c0.y + e0.y));
    pd[1] = cvtpk(relu(c0.z + e0.z), relu(c0.w + e0.w));
    pd[2] = cvtpk(relu(c1.x + e1.x), relu(c1.y + e1.y));
    pd[3] = cvtpk(relu(c1.z + e1.z), relu(c1.w + e1.w));
    accs = MFMA(afs, ld8(WsP + ko), accs);
    accd = MFMA(afd, ld8(WdP + ko), accd);
  }
#pragma unroll
  for (int pp = 0; pp < 4; ++pp) {
    red[w * 2][g * 4 + pp][ln] = accs[pp];
    red[w * 2 + 1][g * 4 + pp][ln] = accd[pp];
  }
  __syncthreads();
  const int j2 = tid >> 4, r = tid & 15;
  float vs = red[0][j2][r] + red[2][j2][r] + red[4][j2][r] + red[6][j2][r] + b2s[r];
  float vd = red[1][j2][r] + red[3][j2][r] + red[5][j2][r] + red[7][j2][r] + b2d[r];
  float ms = vs;
  ms = fmaxf(ms, __shfl_xor(ms, 1)); ms = fmaxf(ms, __shfl_xor(ms, 2));
  ms = fmaxf(ms, __shfl_xor(ms, 4)); ms = fmaxf(ms, __shfl_xor(ms, 8));
  float md = vd;
  md = fmaxf(md, __shfl_xor(md, 1)); md = fmaxf(md, __shfl_xor(md, 2));
  md = fmaxf(md, __shfl_xor(md, 4)); md = fmaxf(md, __shfl_xor(md, 8));
  float es = __expf(vs - ms), ed = __expf(vd - md);
  float ss = es;
  ss += __shfl_xor(ss, 1); ss += __shfl_xor(ss, 2); ss += __shfl_xor(ss, 4); ss += __shfl_xor(ss, 8);
  float sd = ed;
  sd += __shfl_xor(sd, 1); sd += __shfl_xor(sd, 2); sd += __shfl_xor(sd, 4); sd += __shfl_xor(sd, 8);
  const size_t o = (size_t)(jb * 16 + j2) * 6144 + (size_t)i * 32;
  swA[o + r] = f2bf(es / ss);
  swA[o + 16 + r] = f2bf(ed / sd);
}

// ---------------- per-pair weighted message + relu + sum_j -> v_part --------
// js in [0,16): 12 j each. Grid (12,3,16) = 576 blocks.
__global__ __launch_bounds__(256) void k_pairmsg(const unsigned short* __restrict__ swA,
                                                 const unsigned short* __restrict__ twB,
                                                 const float* __restrict__ bm1,
                                                 float* __restrict__ vpart) {
  const int dt = blockIdx.x, it = blockIdx.y, js = blockIdx.z;
  const int tid = threadIdx.x;
  const int w = tid >> 6, l = tid & 63, g = l >> 4, ln = l & 15;
  const int i0 = it * 64 + w * 16;
  const int d0 = dt * 64;
  float bm1v[4];
#pragma unroll
  for (int nt = 0; nt < 4; ++nt) bm1v[nt] = bm1[d0 + nt * 16 + ln];
  f32x4 vacc[4];
#pragma unroll
  for (int nt = 0; nt < 4; ++nt) vacc[nt] = (f32x4){0.f, 0.f, 0.f, 0.f};
  const unsigned short* ap = swA + (size_t)(i0 + ln) * 32 + g * 8 + (size_t)js * 12 * 6144;
  const unsigned short* bp[4];
#pragma unroll
  for (int nt = 0; nt < 4; ++nt)
    bp[nt] = twB + (size_t)(d0 + nt * 16 + ln) * 32 + g * 8 + (size_t)js * 12 * 24576;
  const f32x4 z4 = (f32x4){0.f, 0.f, 0.f, 0.f};
#pragma unroll 4
  for (int jj = 0; jj < 12; ++jj) {
    u16x8 a = ld8(ap + (size_t)jj * 6144);
#pragma unroll
    for (int nt = 0; nt < 4; ++nt) {
      u16x8 b = ld8(bp[nt] + (size_t)jj * 24576);
      f32x4 mf = MFMA(a, b, z4);
#pragma unroll
      for (int pp = 0; pp < 4; ++pp) vacc[nt][pp] += fmaxf(mf[pp] + bm1v[nt], 0.f);
    }
  }
#pragma unroll
  for (int nt = 0; nt < 4; ++nt)
#pragma unroll
    for (int pp = 0; pp < 4; ++pp) {
      const int row = i0 + g * 4 + pp;
      vpart[(size_t)js * 147456 + (size_t)row * H + d0 + nt * 16 + ln] = vacc[nt][pp];
    }
}

__global__ void k_vred(const float* __restrict__ vpart, unsigned short* __restrict__ vhi,
                       unsigned short* __restrict__ vlo) {
  int e = blockIdx.x * 256 + threadIdx.x;  // 147456
  float s = 0.f;
#pragma unroll
  for (int q = 0; q < 16; ++q) s += vpart[(size_t)q * 147456 + e];
  s *= (1.0f / 192.0f);
  unsigned short hi = f2bf(s);
  vhi[e] = hi;
  vlo[e] = f2bf(s - bf2f(hi));
}

__global__ void k_gru(const float* __restrict__ gxp, const float* __restrict__ bcv,
                      const float* __restrict__ gh, float* __restrict__ h,
                      unsigned short* __restrict__ hhi, unsigned short* __restrict__ hlo,
                      float* __restrict__ out, int last) {
  int e = blockIdx.x * 256 + threadIdx.x;  // 147456
  int i = e / H, k = e - i * H;
  size_t base = (size_t)i * GW;
  const size_t S = (size_t)NTOT * GW;
  float rr = gxp[base + k] + gxp[S + base + k] + gxp[2 * S + base + k] +
             gxp[3 * S + base + k] + bcv[k] + gh[base + k];
  float zz = gxp[base + H + k] + gxp[S + base + H + k] + gxp[2 * S + base + H + k] +
             gxp[3 * S + base + H + k] + bcv[H + k] + gh[base + H + k];
  float r = 1.f / (1.f + __expf(-rr));
  float z = 1.f / (1.f + __expf(-zz));
  float nn = gxp[base + 2 * H + k] + gxp[S + base + 2 * H + k] +
             gxp[2 * S + base + 2 * H + k] + gxp[3 * S + base + 2 * H + k] +
             bcv[2 * H + k];
  float n = tanhf(nn + r * gh[base + 2 * H + k]);
  float hv = (1.f - z) * n + z * h[e];
  h[e] = hv;
  unsigned short hi = f2bf(hv);
  hhi[e] = hi;
  hlo[e] = f2bf(hv - bf2f(hi));
  if (last && i >= 64) out[(size_t)(i - 64) * H + k] = hv;
}

// ---------------- launch ----------------------------------------------------

extern "C" void kernel_launch(void* const* d_in, const int* in_sizes, int n_in,
                              void* d_out, int out_size, void* d_ws, size_t ws_size,
                              hipStream_t stream) {
  const float* asp = (const float*)d_in[0];
  const float* qry = (const float*)d_in[1];
  const float* W1s = (const float*)d_in[3];
  const float* b1s = (const float*)d_in[4];
  const float* W2s = (const float*)d_in[5];
  const float* b2s = (const float*)d_in[6];
  const float* W1d = (const float*)d_in[7];
  const float* b1d = (const float*)d_in[8];
  const float* W2d = (const float*)d_in[9];
  const float* b2d = (const float*)d_in[10];
  const float* Rs  = (const float*)d_in[11];
  const float* Rd  = (const float*)d_in[12];
  const float* Wm1 = (const float*)d_in[13];
  const float* bm1 = (const float*)d_in[14];
  const float* Wm2 = (const float*)d_in[15];
  const float* bm2 = (const float*)d_in[16];
  const float* Wih = (const float*)d_in[17];
  const float* Whh = (const float*)d_in[18];
  const float* bih = (const float*)d_in[19];
  const float* bhh = (const float*)d_in[20];
  float* out = (float*)d_out;

  char* p = (char*)d_ws;
  auto take = [&](size_t bytes) {
    char* q = p;
    p += (bytes + 255) & ~(size_t)255;
    return q;
  };
  // ---- step-scratch region, aliased during prep ----
  float* h            = (float*)take((size_t)NTOT * H * 4);
  unsigned short* hhi = (unsigned short*)take((size_t)NTOT * H * 2);
  unsigned short* hlo = (unsigned short*)take((size_t)NTOT * H * 2);
  float* A4           = (float*)take((size_t)NTOT * A4W * 4);
  float* ghb          = (float*)take((size_t)NTOT * GW * 4);
  unsigned short* vhi = (unsigned short*)take((size_t)NTOT * H * 2);
  unsigned short* vlo = (unsigned short*)take((size_t)NTOT * H * 2);
  float* vpart        = (float*)take((size_t)16 * NTOT * H * 4);
  unsigned short* swA = (unsigned short*)take((size_t)NTOT * NTOT * 32 * 2);
  unsigned short* twB = (unsigned short*)take((size_t)NTOT * H * 32 * 2);  // also gx partials
  // ---- permanent weights ----
  unsigned short* RsWt = (unsigned short*)take((size_t)2 * 16 * H * H * 2);
  unsigned short* Wm1bf = (unsigned short*)take((size_t)H * H * 2);
  unsigned short* W2sbf = (unsigned short*)take((size_t)16 * H * 2);
  unsigned short* W2dbf = (unsigned short*)take((size_t)16 * H * 2);
  unsigned short* W1cat = (unsigned short*)take((size_t)A4W * H * 2);
  float* b1cat        = (float*)take((size_t)A4W * 4);
  unsigned short* Whhh = (unsigned short*)take((size_t)GW * H * 2);
  unsigned short* Whhl = (unsigned short*)take((size_t)GW * H * 2);
  unsigned short* Wch  = (unsigned short*)take((size_t)GW * H * 2);
  unsigned short* Wcl  = (unsigned short*)take((size_t)GW * H * 2);
  float* bc           = (float*)take((size_t)GW * 4);
  // ---- prep-phase aliases (within step-scratch, after h/hhi/hlo @1,179,648) ----
  unsigned short* Wm2th = (unsigned short*)((char*)d_ws + 1179648);
  unsigned short* Wm2tl = Wm2th + (size_t)H * H;  // ends ~3.54 MB

  // ---- once-per-launch prep ----
  k_prep<<<5928, 256, 0, stream>>>(Wm1, W2s, W2d, Whh, Wih, Wm2, W1s, W1d, b1s, b1d,
                                   bm2, bih, asp, qry,
                                   Wm1bf, W2sbf, W2dbf, Whhh, Whhl,
                                   Wm2th, Wm2tl, W1cat, b1cat, bc, h, hhi, hlo);
  k_pre2<<<1584, 256, 0, stream>>>(Wm1bf, Rs, Rd, RsWt, Wih, Wm2th, Wm2tl, Wch, Wcl);

  // ---- propagation steps ----
  for (int step = 0; step < 3; ++step) {
    k_tile<<<702, 256, 0, stream>>>(hhi, hlo, W1cat, b1cat, Whhh, Whhl, bhh, RsWt,
                                    A4, ghb, twB);
    k_pairlog<<<dim3(192, 12), 256, 0, stream>>>(A4, W2sbf, W2dbf, b2s, b2d, swA);
    k_pairmsg<<<dim3(12, 3, 16), 256, 0, stream>>>(swA, twB, bm1, vpart);
    k_vred<<<576, 256, 0, stream>>>(vpart, vhi, vlo);
    k_btks<<<dim3(36, 3, 4), 256, 0, stream>>>(vhi, vlo, Wch, Wcl, (float*)twB);
    k_gru<<<576, 256, 0, stream>>>((float*)twB, bc, ghb, h, hhi, hlo, out, step == 2);
  }
  (void)in_sizes; (void)n_in; (void)out_size; (void)ws_size;
}

// Round 17
// 425.173 us; speedup vs baseline: 1.0452x; 1.0452x over previous
//
#include <hip/hip_runtime.h>
#include <hip/hip_bf16.h>

#define H 768
#define NTOT 192
#define A4W 3072
#define GW 2304

typedef __attribute__((ext_vector_type(4))) float f32x4;
typedef __attribute__((ext_vector_type(8))) unsigned short u16x8;
typedef __attribute__((ext_vector_type(4))) unsigned short u16x4;
typedef __attribute__((ext_vector_type(8))) __bf16 bf16x8v;

static __device__ __forceinline__ unsigned short f2bf(float f) {
  __hip_bfloat16 b = __float2bfloat16(f);
  return __builtin_bit_cast(unsigned short, b);
}
static __device__ __forceinline__ float bf2f(unsigned short u) {
  return __bfloat162float(__builtin_bit_cast(__hip_bfloat16, u));
}
static __device__ __forceinline__ f32x4 MFMA(u16x8 a, u16x8 b, f32x4 c) {
  return __builtin_amdgcn_mfma_f32_16x16x32_bf16(
      __builtin_bit_cast(bf16x8v, a), __builtin_bit_cast(bf16x8v, b), c, 0, 0, 0);
}
static __device__ __forceinline__ u16x8 ld8(const unsigned short* p) {
  return *(const u16x8*)p;
}
static __device__ __forceinline__ unsigned int cvtpk(float lo, float hi) {
  unsigned int r;
  asm("v_cvt_pk_bf16_f32 %0, %1, %2" : "=v"(r) : "v"(lo), "v"(hi));
  return r;
}
static __device__ __forceinline__ float relu(float x) { return fmaxf(x, 0.f); }

#define GLDS16(gp, lp)                                                   \
  __builtin_amdgcn_global_load_lds(                                      \
      (const __attribute__((address_space(1))) void*)(gp),               \
      (__attribute__((address_space(3))) void*)(lp), 16, 0, 0)

// ---------------- fused prep: weight conversions + bc + inith --------------
__global__ void k_prep(const float* __restrict__ Wm1, const float* __restrict__ W2s,
                       const float* __restrict__ W2d, const float* __restrict__ Whh,
                       const float* __restrict__ Wih, const float* __restrict__ Wm2,
                       const float* __restrict__ W1s, const float* __restrict__ W1d,
                       const float* __restrict__ b1s, const float* __restrict__ b1d,
                       const float* __restrict__ bm2, const float* __restrict__ bih,
                       const float* __restrict__ asp, const float* __restrict__ qry,
                       unsigned short* __restrict__ Wm1bf, unsigned short* __restrict__ W2sbf,
                       unsigned short* __restrict__ W2dbf, unsigned short* __restrict__ Whhh,
                       unsigned short* __restrict__ Whhl, unsigned short* __restrict__ Wm2th,
                       unsigned short* __restrict__ Wm2tl, unsigned short* __restrict__ W1cat,
                       float* __restrict__ b1cat, float* __restrict__ bc,
                       float* __restrict__ h, unsigned short* __restrict__ hhi,
                       unsigned short* __restrict__ hlo) {
  const int b = blockIdx.x, tid = threadIdx.x;
  if (b < 576) {
    int u = b * 256 + tid;
    float4 v = ((const float4*)Wm1)[u];
    u16x4 o; o[0] = f2bf(v.x); o[1] = f2bf(v.y); o[2] = f2bf(v.z); o[3] = f2bf(v.w);
    ((u16x4*)Wm1bf)[u] = o;
  } else if (b < 588) {
    int u = (b - 576) * 256 + tid;
    float4 v = ((const float4*)W2s)[u];
    u16x4 o; o[0] = f2bf(v.x); o[1] = f2bf(v.y); o[2] = f2bf(v.z); o[3] = f2bf(v.w);
    ((u16x4*)W2sbf)[u] = o;
  } else if (b < 600) {
    int u = (b - 588) * 256 + tid;
    float4 v = ((const float4*)W2d)[u];
    u16x4 o; o[0] = f2bf(v.x); o[1] = f2bf(v.y); o[2] = f2bf(v.z); o[3] = f2bf(v.w);
    ((u16x4*)W2dbf)[u] = o;
  } else if (b < 2328) {
    int u = (b - 600) * 256 + tid;
    float4 v = ((const float4*)Whh)[u];
    u16x4 oh, ol;
#pragma unroll
    for (int j = 0; j < 4; ++j) {
      float f = ((const float*)&v)[j];
      oh[j] = f2bf(f); ol[j] = f2bf(f - bf2f(oh[j]));
    }
    ((u16x4*)Whhh)[u] = oh; ((u16x4*)Whhl)[u] = ol;
  } else if (b < 2904) {
    int u = (b - 2328) * 256 + tid;  // Wm2 f4 index; emit TRANSPOSED hi/lo
    float4 v = ((const float4*)Wm2)[u];
    int e_lin = u * 4;
    int er = e_lin / H, kc = e_lin - er * H;
#pragma unroll
    for (int j = 0; j < 4; ++j) {
      float f = ((const float*)&v)[j];
      unsigned short hi = f2bf(f);
      Wm2th[(size_t)(kc + j) * H + er] = hi;
      Wm2tl[(size_t)(kc + j) * H + er] = f2bf(f - bf2f(hi));
    }
  } else if (b < 5208) {
    int u = (b - 2904) * 256 + tid;  // f4 index into W1cat [3072][768]
    int e = u * 4;
    int row = e / H, k = e - row * H;
    int part = row / H, o = row - part * H;
    const float* W = (part < 2) ? W1s : W1d;
    float4 v = *(const float4*)(W + (size_t)o * (2 * H) + (part & 1) * H + k);
    u16x4 ov; ov[0] = f2bf(v.x); ov[1] = f2bf(v.y); ov[2] = f2bf(v.z); ov[3] = f2bf(v.w);
    *(u16x4*)(W1cat + e) = ov;
    if (u < 768) {
      int e2 = u * 4, pp = e2 / H, oo = e2 - pp * H;
      float4 bv;
      if (pp == 0) bv = *(const float4*)(b1s + oo);
      else if (pp == 2) bv = *(const float4*)(b1d + oo);
      else bv = (float4){0.f, 0.f, 0.f, 0.f};
      *(float4*)(b1cat + e2) = bv;
    }
  } else if (b < 5784) {
    const int w = tid >> 6, l = tid & 63;
    const int gg = (b - 5208) * 4 + w;
    const float* row = Wih + (size_t)gg * H;
    float s = 0.f;
#pragma unroll
    for (int q = 0; q < 12; ++q) s += row[l + q * 64] * bm2[l + q * 64];
#pragma unroll
    for (int m = 32; m; m >>= 1) s += __shfl_xor(s, m);
    if (l == 0) bc[gg] = bih[gg] + s;
  } else {
    int u = (b - 5784) * 256 + tid;  // f4 index, 36864
    float4 v = (u < 12288) ? ((const float4*)asp)[u] : ((const float4*)qry)[u - 12288];
    ((float4*)h)[u] = v;
    u16x4 oh, ol;
#pragma unroll
    for (int j = 0; j < 4; ++j) {
      float f = ((const float*)&v)[j];
      oh[j] = f2bf(f); ol[j] = f2bf(f - bf2f(oh[j]));
    }
    ((u16x4*)hhi)[u] = oh; ((u16x4*)hlo)[u] = ol;
  }
}

// ---------------- merged prep GEMM, 32 KB LDS, 2736 blocks ------------------
// blocks 0..2303: RsW 64x128 tiles (round-11 sync form; A dbuf + early issue).
// blocks 2304..2735: Wc = Wih @ Wm2t^T, 64x64 tiles (serial tail, preserves
// RsW's XCD swizzle phase — round-16 interleave destroyed R locality).
__global__ __launch_bounds__(256) void k_pre2(const unsigned short* __restrict__ Wm1bf,
                                              const float* __restrict__ Rsf,
                                              const float* __restrict__ Rdf,
                                              unsigned short* __restrict__ RsWt,
                                              const float* __restrict__ Wih,
                                              const unsigned short* __restrict__ Bth,
                                              const unsigned short* __restrict__ Btl,
                                              unsigned short* __restrict__ Ch,
                                              unsigned short* __restrict__ Cl) {
  __shared__ unsigned short LDS[16384];  // 32 KB
  const int wg = blockIdx.x;
  const int tid = threadIdx.x, w = tid >> 6, l = tid & 63;
  const int g = l >> 4, ln = l & 15;
  const int srow = l >> 3;
  const int skb = ((l & 7) ^ srow) * 8;
  const int x7 = ln & 7;

  if (wg >= 2304) {
    // --------- Wc: 64x64 tile, BK=64 ---------------------------------------
    unsigned short* Ahl = LDS;
    unsigned short* All = LDS + 4096;
    unsigned short* Bhl = LDS + 8192;
    unsigned short* Bll = LDS + 12288;
    const int bid = wg - 2304;
    const int m0 = (bid / 12) * 64, n0 = (bid % 12) * 64;
    const unsigned short* Bgh = Bth + (size_t)(n0 + srow) * H + skb;
    const unsigned short* Bgl = Btl + (size_t)(n0 + srow) * H + skb;
    f32x4 acc[4];
#pragma unroll
    for (int mi = 0; mi < 4; ++mi) acc[mi] = (f32x4){0.f, 0.f, 0.f, 0.f};
    for (int kb = 0; kb < H; kb += 64) {
#pragma unroll
      for (int c2 = 0; c2 < 2; ++c2) {
        const int c = w * 2 + c2;
        GLDS16(Bgh + (size_t)(c * 8) * H + kb, &Bhl[c * 512]);
        GLDS16(Bgl + (size_t)(c * 8) * H + kb, &Bll[c * 512]);
      }
#pragma unroll
      for (int q = 0; q < 2; ++q) {
        const int idx = q * 256 + tid;
        const int row = idx >> 3, kb8 = idx & 7;
        const float* src = Wih + (size_t)(m0 + row) * H + kb + kb8 * 8;
        float4 v0 = *(const float4*)src;
        float4 v1 = *(const float4*)(src + 4);
        float fv[8] = {v0.x, v0.y, v0.z, v0.w, v1.x, v1.y, v1.z, v1.w};
        u16x8 oh, ol;
#pragma unroll
        for (int jq = 0; jq < 8; ++jq) {
          unsigned short hi = f2bf(fv[jq]);
          oh[jq] = hi;
          ol[jq] = f2bf(fv[jq] - bf2f(hi));
        }
        const int dst = row * 64 + (kb8 ^ (row & 7)) * 8;
        *(u16x8*)&Ahl[dst] = oh;
        *(u16x8*)&All[dst] = ol;
      }
      __syncthreads();
#pragma unroll
      for (int kk = 0; kk < 2; ++kk) {
        const int pb = ((kk * 4 + g) ^ x7) * 8;
        u16x8 bh = ld8(&Bhl[(w * 16 + ln) * 64 + pb]);
        u16x8 bl = ld8(&Bll[(w * 16 + ln) * 64 + pb]);
#pragma unroll
        for (int mi = 0; mi < 4; ++mi) {
          u16x8 ah = ld8(&Ahl[(mi * 16 + ln) * 64 + pb]);
          u16x8 al = ld8(&All[(mi * 16 + ln) * 64 + pb]);
          acc[mi] = MFMA(ah, bh, acc[mi]);
          acc[mi] = MFMA(ah, bl, acc[mi]);
          acc[mi] = MFMA(al, bh, acc[mi]);
        }
      }
      __syncthreads();
    }
#pragma unroll
    for (int mi = 0; mi < 4; ++mi) {
      const int col = n0 + w * 16 + ln;
#pragma unroll
      for (int pp = 0; pp < 4; ++pp) {
        const int row = m0 + mi * 16 + g * 4 + pp;
        const float val = acc[mi][pp];
        unsigned short hi = f2bf(val);
        Ch[(size_t)row * H + col] = hi;
        Cl[(size_t)row * H + col] = f2bf(val - bf2f(hi));
      }
    }
    return;
  }

  // --------- RsW 64(d) x 128(k) tiles; out row = d*32+z --------------------
  unsigned short* Asl0 = LDS;           // 8 KB: 64x64 bf16
  unsigned short* Asl1 = LDS + 4096;    // 8 KB (A double buffer)
  unsigned short* Bsl = LDS + 8192;     // 16 KB: 128x64 bf16
  const int nb = (wg & 7) * 288 + (wg >> 3);       // chunked XCD swizzle (2304=8*288)
  const int z = nb / 72, t5 = nb - z * 72;
  const int d0 = (t5 / 6) * 64, k0 = (t5 % 6) * 128;
  const unsigned short* Ag = Wm1bf + (size_t)(d0 + srow) * H + skb;
  const float* Bg = ((z < 16) ? Rsf : Rdf) + (size_t)(z & 15) * (H * H);
  const int kb8 = tid & 7, rb = tid >> 3;
  const float* Bq = Bg + (size_t)(k0 + rb) * H + kb8 * 8;
  const int bdst = rb * 64 + (kb8 ^ (rb & 7)) * 8;

#define LOADB_(kbv, Ra, Rb)                                  \
  _Pragma("unroll") for (int q = 0; q < 4; ++q) {            \
    const float* s_ = Bq + (size_t)(q * 32) * H + (kbv);     \
    Ra[q] = *(const float4*)s_;                              \
    Rb[q] = *(const float4*)(s_ + 4);                        \
  }
#define WRITEB_(Ra, Rb)                                      \
  _Pragma("unroll") for (int q = 0; q < 4; ++q) {            \
    u16x8 o_; unsigned int* po_ = (unsigned int*)&o_;        \
    po_[0] = cvtpk(Ra[q].x, Ra[q].y);                        \
    po_[1] = cvtpk(Ra[q].z, Ra[q].w);                        \
    po_[2] = cvtpk(Rb[q].x, Rb[q].y);                        \
    po_[3] = cvtpk(Rb[q].z, Rb[q].w);                        \
    *(u16x8*)&Bsl[q * 2048 + bdst] = o_;                     \
  }
#define GLDSA_(kbv, buf)                                     \
  _Pragma("unroll") for (int c2 = 0; c2 < 2; ++c2) {         \
    const int c_ = w * 2 + c2;                               \
    GLDS16(Ag + (size_t)(c_ * 8) * H + (kbv), &(buf)[c_ * 512]); \
  }

  f32x4 acc[4][2];
#pragma unroll
  for (int mi = 0; mi < 4; ++mi)
#pragma unroll
    for (int ni = 0; ni < 2; ++ni) acc[mi][ni] = (f32x4){0.f, 0.f, 0.f, 0.f};
  float4 ra[4], rbv[4];
  GLDSA_(0, Asl0);
  LOADB_(0, ra, rbv);
  WRITEB_(ra, rbv);
  __syncthreads();
#pragma unroll
  for (int t = 0; t < 12; ++t) {
    unsigned short* Acur = (t & 1) ? Asl1 : Asl0;
    unsigned short* Anxt = (t & 1) ? Asl0 : Asl1;
    if (t < 11) {
      GLDSA_((t + 1) * 64, Anxt);      // A(t+1) -> other buffer, issued early
      LOADB_((t + 1) * 64, ra, rbv);   // B(t+1) -> regs, issued early
    }
    __builtin_amdgcn_sched_barrier(0); // pin issues above the MFMA block
#pragma unroll
    for (int kk = 0; kk < 2; ++kk) {
      u16x8 af[4], bf[2];
      const int pb = ((kk * 4 + g) ^ x7) * 8;
#pragma unroll
      for (int mi = 0; mi < 4; ++mi) af[mi] = ld8(&Acur[(mi * 16 + ln) * 64 + pb]);
#pragma unroll
      for (int ni = 0; ni < 2; ++ni) bf[ni] = ld8(&Bsl[(w * 32 + ni * 16 + ln) * 64 + pb]);
#pragma unroll
      for (int mi = 0; mi < 4; ++mi)
#pragma unroll
        for (int ni = 0; ni < 2; ++ni) acc[mi][ni] = MFMA(af[mi], bf[ni], acc[mi][ni]);
    }
    __syncthreads();                   // drains A(t+1)/B(t+1); compute hid most
    if (t < 11) {
      WRITEB_(ra, rbv);                // B regs ready; cvt+ds_write
      __syncthreads();                 // cheap: no outstanding VMEM
    }
  }
#pragma unroll
  for (int mi = 0; mi < 4; ++mi) {
    const int d = d0 + mi * 16 + g * 4;
#pragma unroll
    for (int ni = 0; ni < 2; ++ni) {
      const int k = k0 + w * 32 + ni * 16 + ln;
      unsigned short* o = RsWt + ((size_t)d * 32 + z) * H + k;
#pragma unroll
      for (int pp = 0; pp < 4; ++pp) o[(size_t)pp * 32 * H] = f2bf(acc[mi][ni][pp]);
    }
  }
#undef LOADB_
#undef WRITEB_
#undef GLDSA_
}

// ---------------- K-split(4) hilo GEMM for gx (no bias, raw partials) -------
__global__ __launch_bounds__(256) void k_btks(
    const unsigned short* __restrict__ Ahi, const unsigned short* __restrict__ Alo,
    const unsigned short* __restrict__ Bhi, const unsigned short* __restrict__ Blo,
    float* __restrict__ Cp) {
  const int tid = threadIdx.x;
  const int w = tid >> 6, l = tid & 63, g = l >> 4, ln = l & 15;
  const int m0 = blockIdx.y * 64 + w * 16;
  const int n0 = blockIdx.x * 64;
  const int kh = blockIdx.z, kb0 = kh * 192;
  const unsigned short* aph = Ahi + (size_t)(m0 + ln) * H + kb0 + g * 8;
  const unsigned short* apl = Alo + (size_t)(m0 + ln) * H + kb0 + g * 8;
  const unsigned short* bph[4];
  const unsigned short* bpl[4];
#pragma unroll
  for (int nt = 0; nt < 4; ++nt) {
    bph[nt] = Bhi + (size_t)(n0 + nt * 16 + ln) * H + kb0 + g * 8;
    bpl[nt] = Blo + (size_t)(n0 + nt * 16 + ln) * H + kb0 + g * 8;
  }
  f32x4 acc[4];
#pragma unroll
  for (int nt = 0; nt < 4; ++nt) acc[nt] = (f32x4){0.f, 0.f, 0.f, 0.f};
  u16x8 ah[2], al[2], bh[2][4], bl[2][4];
  ah[0] = ld8(aph);
  al[0] = ld8(apl);
#pragma unroll
  for (int nt = 0; nt < 4; ++nt) { bh[0][nt] = ld8(bph[nt]); bl[0][nt] = ld8(bpl[nt]); }
#pragma unroll
  for (int t = 0; t < 6; ++t) {
    const int cur = t & 1, nxt = cur ^ 1;
    if (t < 5) {
      const int ko = (t + 1) * 32;
      ah[nxt] = ld8(aph + ko);
      al[nxt] = ld8(apl + ko);
#pragma unroll
      for (int nt = 0; nt < 4; ++nt) {
        bh[nxt][nt] = ld8(bph[nt] + ko);
        bl[nxt][nt] = ld8(bpl[nt] + ko);
      }
    }
#pragma unroll
    for (int nt = 0; nt < 4; ++nt) {
      acc[nt] = MFMA(ah[cur], bh[cur][nt], acc[nt]);
      acc[nt] = MFMA(ah[cur], bl[cur][nt], acc[nt]);
      acc[nt] = MFMA(al[cur], bh[cur][nt], acc[nt]);
    }
  }
#pragma unroll
  for (int nt = 0; nt < 4; ++nt) {
    const int col = n0 + nt * 16 + ln;
#pragma unroll
    for (int pp = 0; pp < 4; ++pp) {
      const int row = m0 + g * 4 + pp;
      Cp[(size_t)kh * (NTOT * GW) + (size_t)row * GW + col] = acc[nt][pp];
    }
  }
}

// ---------------- per-step LDS-staged tiled GEMM: gh | A4 | twB -------------
// 64(M) x 128(N) tiles, BK=64. Bijective XCD swizzle.
// Paths 1/2: A+B double-buffered, early issue. Path 0 (gh, hilo): original.
__global__ __launch_bounds__(256) void k_tile(
    const unsigned short* __restrict__ hhi, const unsigned short* __restrict__ hlo,
    const unsigned short* __restrict__ W1cat, const float* __restrict__ b1cat,
    const unsigned short* __restrict__ Whhh, const unsigned short* __restrict__ Whhl,
    const float* __restrict__ bhh, const unsigned short* __restrict__ RsWt,
    float* __restrict__ A4, float* __restrict__ ghb, unsigned short* __restrict__ twB) {
  __shared__ unsigned short LDS[24576];  // 48 KB
  const int orig = blockIdx.x;           // 702 blocks
  const int qq = 87, rr = 6;             // 702 = 8*87 + 6
  const int xcd = orig & 7, idx = orig >> 3;
  const int bid = (xcd < rr ? xcd * (qq + 1) : rr * (qq + 1) + (xcd - rr) * qq) + idx;
  const int tid = threadIdx.x, w = tid >> 6, l = tid & 63, g = l >> 4, ln = l & 15;
  int path, m, n;
  if (bid < 54)       { path = 0; n = bid / 3;         m = bid % 3; }
  else if (bid < 126) { path = 1; n = (bid - 54) / 3;  m = (bid - 54) % 3; }
  else                { path = 2; n = (bid - 126) / 3; m = (bid - 126) % 3; }
  const int m0 = m * 64, n0 = n * 128;
  const int srow = l >> 3;
  const int skb = ((l & 7) ^ srow) * 8;
  const int x7 = ln & 7;
  f32x4 acc[4][2];
#pragma unroll
  for (int mi = 0; mi < 4; ++mi)
#pragma unroll
    for (int ni = 0; ni < 2; ++ni) acc[mi][ni] = (f32x4){0.f, 0.f, 0.f, 0.f};

  if (path == 0) {
    unsigned short* Ah = LDS;
    unsigned short* Al = LDS + 4096;
    unsigned short* Bh = LDS + 8192;
    unsigned short* Bl = LDS + 16384;
    const unsigned short* Agh = hhi + (size_t)(m0 + srow) * H + skb;
    const unsigned short* Agl = hlo + (size_t)(m0 + srow) * H + skb;
    const unsigned short* Bgh = Whhh + (size_t)(n0 + srow) * H + skb;
    const unsigned short* Bgl = Whhl + (size_t)(n0 + srow) * H + skb;
    for (int kb = 0; kb < H; kb += 64) {
#pragma unroll
      for (int c2 = 0; c2 < 2; ++c2) {
        const int c = w * 2 + c2;
        GLDS16(Agh + (size_t)(c * 8) * H + kb, &Ah[c * 512]);
        GLDS16(Agl + (size_t)(c * 8) * H + kb, &Al[c * 512]);
      }
#pragma unroll
      for (int c4 = 0; c4 < 4; ++c4) {
        const int c = w * 4 + c4;
        GLDS16(Bgh + (size_t)(c * 8) * H + kb, &Bh[c * 512]);
        GLDS16(Bgl + (size_t)(c * 8) * H + kb, &Bl[c * 512]);
      }
      __syncthreads();
#pragma unroll
      for (int kk = 0; kk < 2; ++kk) {
        const int pb = ((kk * 4 + g) ^ x7) * 8;
        u16x8 af[4], bf[2], alf[4], blf[2];
#pragma unroll
        for (int mi = 0; mi < 4; ++mi) {
          af[mi] = ld8(&Ah[(mi * 16 + ln) * 64 + pb]);
          alf[mi] = ld8(&Al[(mi * 16 + ln) * 64 + pb]);
        }
#pragma unroll
        for (int ni = 0; ni < 2; ++ni) {
          bf[ni] = ld8(&Bh[(w * 32 + ni * 16 + ln) * 64 + pb]);
          blf[ni] = ld8(&Bl[(w * 32 + ni * 16 + ln) * 64 + pb]);
        }
#pragma unroll
        for (int mi = 0; mi < 4; ++mi)
#pragma unroll
          for (int ni = 0; ni < 2; ++ni) {
            acc[mi][ni] = MFMA(af[mi], bf[ni], acc[mi][ni]);
            acc[mi][ni] = MFMA(af[mi], blf[ni], acc[mi][ni]);
            acc[mi][ni] = MFMA(alf[mi], bf[ni], acc[mi][ni]);
          }
      }
      __syncthreads();
    }
#pragma unroll
    for (int mi = 0; mi < 4; ++mi)
#pragma unroll
      for (int ni = 0; ni < 2; ++ni) {
        const int col = n0 + w * 32 + ni * 16 + ln;
        const float bv = bhh[col];
#pragma unroll
        for (int pp = 0; pp < 4; ++pp) {
          const int row = m0 + mi * 16 + g * 4 + pp;
          ghb[(size_t)row * GW + col] = acc[mi][ni][pp] + bv;
        }
      }
    return;
  }

  unsigned short* As0 = LDS;            // 8 KB (64x64)
  unsigned short* As1 = LDS + 4096;
  unsigned short* Bs0 = LDS + 8192;     // 16 KB (128x64)
  unsigned short* Bs1 = LDS + 16384;
  const unsigned short* Bsrc = (path == 1) ? W1cat : RsWt;
  const unsigned short* Agh = hhi + (size_t)(m0 + srow) * H + skb;
  const unsigned short* Bgh = Bsrc + (size_t)(n0 + srow) * H + skb;

#define GLDSA2_(kbv, buf)                                    \
  _Pragma("unroll") for (int c2 = 0; c2 < 2; ++c2) {         \
    const int c_ = w * 2 + c2;                               \
    GLDS16(Agh + (size_t)(c_ * 8) * H + (kbv), &(buf)[c_ * 512]); \
  }
#define GLDSB2_(kbv, buf)                                    \
  _Pragma("unroll") for (int c4 = 0; c4 < 4; ++c4) {         \
    const int c_ = w * 4 + c4;                               \
    GLDS16(Bgh + (size_t)(c_ * 8) * H + (kbv), &(buf)[c_ * 512]); \
  }

  GLDSA2_(0, As0);
  GLDSB2_(0, Bs0);
  __syncthreads();
#pragma unroll
  for (int t = 0; t < 12; ++t) {
    unsigned short* Acur = (t & 1) ? As1 : As0;
    unsigned short* Bcur = (t & 1) ? Bs1 : Bs0;
    unsigned short* Anxt = (t & 1) ? As0 : As1;
    unsigned short* Bnxt = (t & 1) ? Bs0 : Bs1;
    if (t < 11) {
      GLDSA2_((t + 1) * 64, Anxt);
      GLDSB2_((t + 1) * 64, Bnxt);
    }
    __builtin_amdgcn_sched_barrier(0);
#pragma unroll
    for (int kk = 0; kk < 2; ++kk) {
      const int pb = ((kk * 4 + g) ^ x7) * 8;
      u16x8 af[4], bf[2];
#pragma unroll
      for (int mi = 0; mi < 4; ++mi) af[mi] = ld8(&Acur[(mi * 16 + ln) * 64 + pb]);
#pragma unroll
      for (int ni = 0; ni < 2; ++ni) bf[ni] = ld8(&Bcur[(w * 32 + ni * 16 + ln) * 64 + pb]);
#pragma unroll
      for (int mi = 0; mi < 4; ++mi)
#pragma unroll
        for (int ni = 0; ni < 2; ++ni) acc[mi][ni] = MFMA(af[mi], bf[ni], acc[mi][ni]);
    }
    __syncthreads();
  }
#undef GLDSA2_
#undef GLDSB2_

  if (path == 2) {
#pragma unroll
    for (int mi = 0; mi < 4; ++mi)
#pragma unroll
      for (int ni = 0; ni < 2; ++ni) {
        const int c = n0 + w * 32 + ni * 16 + ln;
#pragma unroll
        for (int pp = 0; pp < 4; ++pp) {
          const int j = m0 + mi * 16 + g * 4 + pp;
          twB[(size_t)j * 24576 + c] = f2bf(acc[mi][ni][pp]);
        }
      }
  } else {
#pragma unroll
    for (int mi = 0; mi < 4; ++mi)
#pragma unroll
      for (int ni = 0; ni < 2; ++ni) {
        const int col = n0 + w * 32 + ni * 16 + ln;
        const float bv = b1cat[col];
#pragma unroll
        for (int pp = 0; pp < 4; ++pp) {
          const int row = m0 + mi * 16 + g * 4 + pp;
          A4[(size_t)row * A4W + col] = acc[mi][ni][pp] + bv;
        }
      }
  }
}

// ---------------- pair logits + softmax -> swA[j][i][32] (bf16) -------------
__global__ __launch_bounds__(256) void k_pairlog(
    const float* __restrict__ A4, const unsigned short* __restrict__ W2sbf,
    const unsigned short* __restrict__ W2dbf, const float* __restrict__ b2s,
    const float* __restrict__ b2d, unsigned short* __restrict__ swA) {
  __shared__ float red[8][16][17];
  const int i = blockIdx.x, jb = blockIdx.y;
  const int tid = threadIdx.x, w = tid >> 6, l = tid & 63;
  const int g = l >> 4, ln = l & 15;
  const int j = jb * 16 + ln;
  const float* BsP = A4 + (size_t)j * A4W + 768 + g * 8;
  const float* BdP = A4 + (size_t)j * A4W + 2304 + g * 8;
  const float* AsP = A4 + (size_t)i * A4W + g * 8;
  const float* AdP = A4 + (size_t)i * A4W + 1536 + g * 8;
  const unsigned short* WsP = W2sbf + (size_t)ln * H + g * 8;
  const unsigned short* WdP = W2dbf + (size_t)ln * H + g * 8;
  f32x4 accs = (f32x4){0.f, 0.f, 0.f, 0.f}, accd = (f32x4){0.f, 0.f, 0.f, 0.f};
#pragma unroll
  for (int tt = 0; tt < 6; ++tt) {
    const int ko = (w * 6 + tt) * 32;
    float4 b0 = *(const float4*)(BsP + ko), b1 = *(const float4*)(BsP + ko + 4);
    float4 a0 = *(const float4*)(AsP + ko), a1 = *(const float4*)(AsP + ko + 4);
    float4 e0 = *(const float4*)(BdP + ko), e1 = *(const float4*)(BdP + ko + 4);
    float4 c0 = *(const float4*)(AdP + ko), c1 = *(const float4*)(AdP + ko + 4);
    u16x8 afs, afd;
    unsigned int* ps = (unsigned int*)&afs;
    ps[0] = cvtpk(relu(a0.x + b0.x), relu(a0.y + b0.y));
    ps[1] = cvtpk(relu(a0.z + b0.z), relu(a0.w + b0.w));
    ps[2] = cvtpk(relu(a1.x + b1.x), relu(a1.y + b1.y));
    ps[3] = cvtpk(relu(a1.z + b1.z), relu(a1.w + b1.w));
    unsigned int* pd = (unsigned int*)&afd;
    pd[0] = cvtpk(relu(c0.x + e0.x), relu(c0.y + e0.y));
    pd[1] = cvtpk(relu(c0.z + e0.z), relu(c0.w + e0.w));
    pd[2] = cvtpk(relu(c1.x + e1.x), relu(c1.y + e1.y));
    pd[3] = cvtpk(relu(c1.z + e1.z), relu(c1.w + e1.w));
    accs = MFMA(afs, ld8(WsP + ko), accs);
    accd = MFMA(afd, ld8(WdP + ko), accd);
  }
#pragma unroll
  for (int pp = 0; pp < 4; ++pp) {
    red[w * 2][g * 4 + pp][ln] = accs[pp];
    red[w * 2 + 1][g * 4 + pp][ln] = accd[pp];
  }
  __syncthreads();
  const int j2 = tid >> 4, r = tid & 15;
  float vs = red[0][j2][r] + red[2][j2][r] + red[4][j2][r] + red[6][j2][r] + b2s[r];
  float vd = red[1][j2][r] + red[3][j2][r] + red[5][j2][r] + red[7][j2][r] + b2d[r];
  float ms = vs;
  ms = fmaxf(ms, __shfl_xor(ms, 1)); ms = fmaxf(ms, __shfl_xor(ms, 2));
  ms = fmaxf(ms, __shfl_xor(ms, 4)); ms = fmaxf(ms, __shfl_xor(ms, 8));
  float md = vd;
  md = fmaxf(md, __shfl_xor(md, 1)); md = fmaxf(md, __shfl_xor(md, 2));
  md = fmaxf(md, __shfl_xor(md, 4)); md = fmaxf(md, __shfl_xor(md, 8));
  float es = __expf(vs - ms), ed = __expf(vd - md);
  float ss = es;
  ss += __shfl_xor(ss, 1); ss += __shfl_xor(ss, 2); ss += __shfl_xor(ss, 4); ss += __shfl_xor(ss, 8);
  float sd = ed;
  sd += __shfl_xor(sd, 1); sd += __shfl_xor(sd, 2); sd += __shfl_xor(sd, 4); sd += __shfl_xor(sd, 8);
  const size_t o = (size_t)(jb * 16 + j2) * 6144 + (size_t)i * 32;
  swA[o + r] = f2bf(es / ss);
  swA[o + 16 + r] = f2bf(ed / sd);
}

// ---------------- per-pair weighted message + relu + sum_j -> v_part --------
// js in [0,16): 12 j each. Grid (12,3,16) = 576 blocks.
__global__ __launch_bounds__(256) void k_pairmsg(const unsigned short* __restrict__ swA,
                                                 const unsigned short* __restrict__ twB,
                                                 const float* __restrict__ bm1,
                                                 float* __restrict__ vpart) {
  const int dt = blockIdx.x, it = blockIdx.y, js = blockIdx.z;
  const int tid = threadIdx.x;
  const int w = tid >> 6, l = tid & 63, g = l >> 4, ln = l & 15;
  const int i0 = it * 64 + w * 16;
  const int d0 = dt * 64;
  float bm1v[4];
#pragma unroll
  for (int nt = 0; nt < 4; ++nt) bm1v[nt] = bm1[d0 + nt * 16 + ln];
  f32x4 vacc[4];
#pragma unroll
  for (int nt = 0; nt < 4; ++nt) vacc[nt] = (f32x4){0.f, 0.f, 0.f, 0.f};
  const unsigned short* ap = swA + (size_t)(i0 + ln) * 32 + g * 8 + (size_t)js * 12 * 6144;
  const unsigned short* bp[4];
#pragma unroll
  for (int nt = 0; nt < 4; ++nt)
    bp[nt] = twB + (size_t)(d0 + nt * 16 + ln) * 32 + g * 8 + (size_t)js * 12 * 24576;
  const f32x4 z4 = (f32x4){0.f, 0.f, 0.f, 0.f};
#pragma unroll 4
  for (int jj = 0; jj < 12; ++jj) {
    u16x8 a = ld8(ap + (size_t)jj * 6144);
#pragma unroll
    for (int nt = 0; nt < 4; ++nt) {
      u16x8 b = ld8(bp[nt] + (size_t)jj * 24576);
      f32x4 mf = MFMA(a, b, z4);
#pragma unroll
      for (int pp = 0; pp < 4; ++pp) vacc[nt][pp] += fmaxf(mf[pp] + bm1v[nt], 0.f);
    }
  }
#pragma unroll
  for (int nt = 0; nt < 4; ++nt)
#pragma unroll
    for (int pp = 0; pp < 4; ++pp) {
      const int row = i0 + g * 4 + pp;
      vpart[(size_t)js * 147456 + (size_t)row * H + d0 + nt * 16 + ln] = vacc[nt][pp];
    }
}

__global__ void k_vred(const float* __restrict__ vpart, unsigned short* __restrict__ vhi,
                       unsigned short* __restrict__ vlo) {
  int e = blockIdx.x * 256 + threadIdx.x;  // 147456
  float s = 0.f;
#pragma unroll
  for (int q = 0; q < 16; ++q) s += vpart[(size_t)q * 147456 + e];
  s *= (1.0f / 192.0f);
  unsigned short hi = f2bf(s);
  vhi[e] = hi;
  vlo[e] = f2bf(s - bf2f(hi));
}

__global__ void k_gru(const float* __restrict__ gxp, const float* __restrict__ bcv,
                      const float* __restrict__ gh, float* __restrict__ h,
                      unsigned short* __restrict__ hhi, unsigned short* __restrict__ hlo,
                      float* __restrict__ out, int last) {
  int e = blockIdx.x * 256 + threadIdx.x;  // 147456
  int i = e / H, k = e - i * H;
  size_t base = (size_t)i * GW;
  const size_t S = (size_t)NTOT * GW;
  float rr = gxp[base + k] + gxp[S + base + k] + gxp[2 * S + base + k] +
             gxp[3 * S + base + k] + bcv[k] + gh[base + k];
  float zz = gxp[base + H + k] + gxp[S + base + H + k] + gxp[2 * S + base + H + k] +
             gxp[3 * S + base + H + k] + bcv[H + k] + gh[base + H + k];
  float r = 1.f / (1.f + __expf(-rr));
  float z = 1.f / (1.f + __expf(-zz));
  float nn = gxp[base + 2 * H + k] + gxp[S + base + 2 * H + k] +
             gxp[2 * S + base + 2 * H + k] + gxp[3 * S + base + 2 * H + k] +
             bcv[2 * H + k];
  float n = tanhf(nn + r * gh[base + 2 * H + k]);
  float hv = (1.f - z) * n + z * h[e];
  h[e] = hv;
  unsigned short hi = f2bf(hv);
  hhi[e] = hi;
  hlo[e] = f2bf(hv - bf2f(hi));
  if (last && i >= 64) out[(size_t)(i - 64) * H + k] = hv;
}

// ---------------- launch ----------------------------------------------------

extern "C" void kernel_launch(void* const* d_in, const int* in_sizes, int n_in,
                              void* d_out, int out_size, void* d_ws, size_t ws_size,
                              hipStream_t stream) {
  const float* asp = (const float*)d_in[0];
  const float* qry = (const float*)d_in[1];
  const float* W1s = (const float*)d_in[3];
  const float* b1s = (const float*)d_in[4];
  const float* W2s = (const float*)d_in[5];
  const float* b2s = (const float*)d_in[6];
  const float* W1d = (const float*)d_in[7];
  const float* b1d = (const float*)d_in[8];
  const float* W2d = (const float*)d_in[9];
  const float* b2d = (const float*)d_in[10];
  const float* Rs  = (const float*)d_in[11];
  const float* Rd  = (const float*)d_in[12];
  const float* Wm1 = (const float*)d_in[13];
  const float* bm1 = (const float*)d_in[14];
  const float* Wm2 = (const float*)d_in[15];
  const float* bm2 = (const float*)d_in[16];
  const float* Wih = (const float*)d_in[17];
  const float* Whh = (const float*)d_in[18];
  const float* bih = (const float*)d_in[19];
  const float* bhh = (const float*)d_in[20];
  float* out = (float*)d_out;

  char* p = (char*)d_ws;
  auto take = [&](size_t bytes) {
    char* q = p;
    p += (bytes + 255) & ~(size_t)255;
    return q;
  };
  // ---- step-scratch region, aliased during prep ----
  float* h            = (float*)take((size_t)NTOT * H * 4);
  unsigned short* hhi = (unsigned short*)take((size_t)NTOT * H * 2);
  unsigned short* hlo = (unsigned short*)take((size_t)NTOT * H * 2);
  float* A4           = (float*)take((size_t)NTOT * A4W * 4);
  float* ghb          = (float*)take((size_t)NTOT * GW * 4);
  unsigned short* vhi = (unsigned short*)take((size_t)NTOT * H * 2);
  unsigned short* vlo = (unsigned short*)take((size_t)NTOT * H * 2);
  float* vpart        = (float*)take((size_t)16 * NTOT * H * 4);
  unsigned short* swA = (unsigned short*)take((size_t)NTOT * NTOT * 32 * 2);
  unsigned short* twB = (unsigned short*)take((size_t)NTOT * H * 32 * 2);  // also gx partials
  // ---- permanent weights ----
  unsigned short* RsWt = (unsigned short*)take((size_t)2 * 16 * H * H * 2);
  unsigned short* Wm1bf = (unsigned short*)take((size_t)H * H * 2);
  unsigned short* W2sbf = (unsigned short*)take((size_t)16 * H * 2);
  unsigned short* W2dbf = (unsigned short*)take((size_t)16 * H * 2);
  unsigned short* W1cat = (unsigned short*)take((size_t)A4W * H * 2);
  float* b1cat        = (float*)take((size_t)A4W * 4);
  unsigned short* Whhh = (unsigned short*)take((size_t)GW * H * 2);
  unsigned short* Whhl = (unsigned short*)take((size_t)GW * H * 2);
  unsigned short* Wch  = (unsigned short*)take((size_t)GW * H * 2);
  unsigned short* Wcl  = (unsigned short*)take((size_t)GW * H * 2);
  float* bc           = (float*)take((size_t)GW * 4);
  // ---- prep-phase aliases (within step-scratch, after h/hhi/hlo @1,179,648) ----
  unsigned short* Wm2th = (unsigned short*)((char*)d_ws + 1179648);
  unsigned short* Wm2tl = Wm2th + (size_t)H * H;  // ends ~3.54 MB

  // ---- once-per-launch prep ----
  k_prep<<<5928, 256, 0, stream>>>(Wm1, W2s, W2d, Whh, Wih, Wm2, W1s, W1d, b1s, b1d,
                                   bm2, bih, asp, qry,
                                   Wm1bf, W2sbf, W2dbf, Whhh, Whhl,
                                   Wm2th, Wm2tl, W1cat, b1cat, bc, h, hhi, hlo);
  k_pre2<<<2736, 256, 0, stream>>>(Wm1bf, Rs, Rd, RsWt, Wih, Wm2th, Wm2tl, Wch, Wcl);

  // ---- propagation steps ----
  for (int step = 0; step < 3; ++step) {
    k_tile<<<702, 256, 0, stream>>>(hhi, hlo, W1cat, b1cat, Whhh, Whhl, bhh, RsWt,
                                    A4, ghb, twB);
    k_pairlog<<<dim3(192, 12), 256, 0, stream>>>(A4, W2sbf, W2dbf, b2s, b2d, swA);
    k_pairmsg<<<dim3(12, 3, 16), 256, 0, stream>>>(swA, twB, bm1, vpart);
    k_vred<<<576, 256, 0, stream>>>(vpart, vhi, vlo);
    k_btks<<<dim3(36, 3, 4), 256, 0, stream>>>(vhi, vlo, Wch, Wcl, (float*)twB);
    k_gru<<<576, 256, 0, stream>>>((float*)twB, bc, ghb, h, hhi, hlo, out, step == 2);
  }
  (void)in_sizes; (void)n_in; (void)out_size; (void)ws_size;
}

// Round 18
// 414.088 us; speedup vs baseline: 1.0732x; 1.0268x over previous
//
#include <hip/hip_runtime.h>
#include <hip/hip_bf16.h>

#define H 768
#define NTOT 192
#define A4W 3072
#define GW 2304

typedef __attribute__((ext_vector_type(4))) float f32x4;
typedef __attribute__((ext_vector_type(8))) unsigned short u16x8;
typedef __attribute__((ext_vector_type(4))) unsigned short u16x4;
typedef __attribute__((ext_vector_type(8))) __bf16 bf16x8v;

static __device__ __forceinline__ unsigned short f2bf(float f) {
  __hip_bfloat16 b = __float2bfloat16(f);
  return __builtin_bit_cast(unsigned short, b);
}
static __device__ __forceinline__ float bf2f(unsigned short u) {
  return __bfloat162float(__builtin_bit_cast(__hip_bfloat16, u));
}
static __device__ __forceinline__ f32x4 MFMA(u16x8 a, u16x8 b, f32x4 c) {
  return __builtin_amdgcn_mfma_f32_16x16x32_bf16(
      __builtin_bit_cast(bf16x8v, a), __builtin_bit_cast(bf16x8v, b), c, 0, 0, 0);
}
static __device__ __forceinline__ u16x8 ld8(const unsigned short* p) {
  return *(const u16x8*)p;
}
static __device__ __forceinline__ unsigned int cvtpk(float lo, float hi) {
  unsigned int r;
  asm("v_cvt_pk_bf16_f32 %0, %1, %2" : "=v"(r) : "v"(lo), "v"(hi));
  return r;
}
static __device__ __forceinline__ float relu(float x) { return fmaxf(x, 0.f); }

#define GLDS16(gp, lp)                                                   \
  __builtin_amdgcn_global_load_lds(                                      \
      (const __attribute__((address_space(1))) void*)(gp),               \
      (__attribute__((address_space(3))) void*)(lp), 16, 0, 0)

// ---------------- fused prep: weight conversions + bc + inith --------------
__global__ void k_prep(const float* __restrict__ Wm1, const float* __restrict__ W2s,
                       const float* __restrict__ W2d, const float* __restrict__ Whh,
                       const float* __restrict__ Wih, const float* __restrict__ Wm2,
                       const float* __restrict__ W1s, const float* __restrict__ W1d,
                       const float* __restrict__ b1s, const float* __restrict__ b1d,
                       const float* __restrict__ bm2, const float* __restrict__ bih,
                       const float* __restrict__ asp, const float* __restrict__ qry,
                       unsigned short* __restrict__ Wm1bf, unsigned short* __restrict__ W2sbf,
                       unsigned short* __restrict__ W2dbf, unsigned short* __restrict__ Whhh,
                       unsigned short* __restrict__ Whhl, unsigned short* __restrict__ Wm2th,
                       unsigned short* __restrict__ Wm2tl, unsigned short* __restrict__ W1cat,
                       float* __restrict__ b1cat, float* __restrict__ bc,
                       float* __restrict__ h, unsigned short* __restrict__ hhi,
                       unsigned short* __restrict__ hlo) {
  const int b = blockIdx.x, tid = threadIdx.x;
  if (b < 576) {
    int u = b * 256 + tid;
    float4 v = ((const float4*)Wm1)[u];
    u16x4 o; o[0] = f2bf(v.x); o[1] = f2bf(v.y); o[2] = f2bf(v.z); o[3] = f2bf(v.w);
    ((u16x4*)Wm1bf)[u] = o;
  } else if (b < 588) {
    int u = (b - 576) * 256 + tid;
    float4 v = ((const float4*)W2s)[u];
    u16x4 o; o[0] = f2bf(v.x); o[1] = f2bf(v.y); o[2] = f2bf(v.z); o[3] = f2bf(v.w);
    ((u16x4*)W2sbf)[u] = o;
  } else if (b < 600) {
    int u = (b - 588) * 256 + tid;
    float4 v = ((const float4*)W2d)[u];
    u16x4 o; o[0] = f2bf(v.x); o[1] = f2bf(v.y); o[2] = f2bf(v.z); o[3] = f2bf(v.w);
    ((u16x4*)W2dbf)[u] = o;
  } else if (b < 2328) {
    int u = (b - 600) * 256 + tid;
    float4 v = ((const float4*)Whh)[u];
    u16x4 oh, ol;
#pragma unroll
    for (int j = 0; j < 4; ++j) {
      float f = ((const float*)&v)[j];
      oh[j] = f2bf(f); ol[j] = f2bf(f - bf2f(oh[j]));
    }
    ((u16x4*)Whhh)[u] = oh; ((u16x4*)Whhl)[u] = ol;
  } else if (b < 2904) {
    int u = (b - 2328) * 256 + tid;  // Wm2 f4 index; emit TRANSPOSED hi/lo
    float4 v = ((const float4*)Wm2)[u];
    int e_lin = u * 4;
    int er = e_lin / H, kc = e_lin - er * H;
#pragma unroll
    for (int j = 0; j < 4; ++j) {
      float f = ((const float*)&v)[j];
      unsigned short hi = f2bf(f);
      Wm2th[(size_t)(kc + j) * H + er] = hi;
      Wm2tl[(size_t)(kc + j) * H + er] = f2bf(f - bf2f(hi));
    }
  } else if (b < 5208) {
    int u = (b - 2904) * 256 + tid;  // f4 index into W1cat [3072][768]
    int e = u * 4;
    int row = e / H, k = e - row * H;
    int part = row / H, o = row - part * H;
    const float* W = (part < 2) ? W1s : W1d;
    float4 v = *(const float4*)(W + (size_t)o * (2 * H) + (part & 1) * H + k);
    u16x4 ov; ov[0] = f2bf(v.x); ov[1] = f2bf(v.y); ov[2] = f2bf(v.z); ov[3] = f2bf(v.w);
    *(u16x4*)(W1cat + e) = ov;
    if (u < 768) {
      int e2 = u * 4, pp = e2 / H, oo = e2 - pp * H;
      float4 bv;
      if (pp == 0) bv = *(const float4*)(b1s + oo);
      else if (pp == 2) bv = *(const float4*)(b1d + oo);
      else bv = (float4){0.f, 0.f, 0.f, 0.f};
      *(float4*)(b1cat + e2) = bv;
    }
  } else if (b < 5784) {
    const int w = tid >> 6, l = tid & 63;
    const int gg = (b - 5208) * 4 + w;
    const float* row = Wih + (size_t)gg * H;
    float s = 0.f;
#pragma unroll
    for (int q = 0; q < 12; ++q) s += row[l + q * 64] * bm2[l + q * 64];
#pragma unroll
    for (int m = 32; m; m >>= 1) s += __shfl_xor(s, m);
    if (l == 0) bc[gg] = bih[gg] + s;
  } else {
    int u = (b - 5784) * 256 + tid;  // f4 index, 36864
    float4 v = (u < 12288) ? ((const float4*)asp)[u] : ((const float4*)qry)[u - 12288];
    ((float4*)h)[u] = v;
    u16x4 oh, ol;
#pragma unroll
    for (int j = 0; j < 4; ++j) {
      float f = ((const float*)&v)[j];
      oh[j] = f2bf(f); ol[j] = f2bf(f - bf2f(oh[j]));
    }
    ((u16x4*)hhi)[u] = oh; ((u16x4*)hlo)[u] = ol;
  }
}

// ---------------- merged prep GEMM, 48 KB LDS, 1584 blocks ------------------
// blocks 0..431: Wc = Wih @ Wm2t^T (64x64) — dispatched FIRST so they overlap
//   RsW's ramp instead of forming a serial tail.
// blocks 432..1583: RsW 128x128 (round-11/14 proven loop). 432%8==0 keeps the
//   XCD-swizzle phase identical to round 14 (round-16 lesson: phase matters).
__global__ __launch_bounds__(256) void k_pre2(const unsigned short* __restrict__ Wm1bf,
                                              const float* __restrict__ Rsf,
                                              const float* __restrict__ Rdf,
                                              unsigned short* __restrict__ RsWt,
                                              const float* __restrict__ Wih,
                                              const unsigned short* __restrict__ Bth,
                                              const unsigned short* __restrict__ Btl,
                                              unsigned short* __restrict__ Ch,
                                              unsigned short* __restrict__ Cl) {
  __shared__ unsigned short LDS[24576];  // 48 KB
  const int wg = blockIdx.x;
  const int tid = threadIdx.x, w = tid >> 6, l = tid & 63;
  const int g = l >> 4, ln = l & 15;
  const int srow = l >> 3;
  const int skb = ((l & 7) ^ srow) * 8;
  const int x7 = ln & 7;

  if (wg < 432) {
    // --------- Wc: 64x64 tile, BK=64 ---------------------------------------
    unsigned short* Ahl = LDS;
    unsigned short* All = LDS + 4096;
    unsigned short* Bhl = LDS + 8192;
    unsigned short* Bll = LDS + 12288;
    const int bid = wg;
    const int m0 = (bid / 12) * 64, n0 = (bid % 12) * 64;
    const unsigned short* Bgh = Bth + (size_t)(n0 + srow) * H + skb;
    const unsigned short* Bgl = Btl + (size_t)(n0 + srow) * H + skb;
    f32x4 acc[4];
#pragma unroll
    for (int mi = 0; mi < 4; ++mi) acc[mi] = (f32x4){0.f, 0.f, 0.f, 0.f};
    for (int kb = 0; kb < H; kb += 64) {
#pragma unroll
      for (int c2 = 0; c2 < 2; ++c2) {
        const int c = w * 2 + c2;
        GLDS16(Bgh + (size_t)(c * 8) * H + kb, &Bhl[c * 512]);
        GLDS16(Bgl + (size_t)(c * 8) * H + kb, &Bll[c * 512]);
      }
#pragma unroll
      for (int q = 0; q < 2; ++q) {
        const int idx = q * 256 + tid;
        const int row = idx >> 3, kb8 = idx & 7;
        const float* src = Wih + (size_t)(m0 + row) * H + kb + kb8 * 8;
        float4 v0 = *(const float4*)src;
        float4 v1 = *(const float4*)(src + 4);
        float fv[8] = {v0.x, v0.y, v0.z, v0.w, v1.x, v1.y, v1.z, v1.w};
        u16x8 oh, ol;
#pragma unroll
        for (int jq = 0; jq < 8; ++jq) {
          unsigned short hi = f2bf(fv[jq]);
          oh[jq] = hi;
          ol[jq] = f2bf(fv[jq] - bf2f(hi));
        }
        const int dst = row * 64 + (kb8 ^ (row & 7)) * 8;
        *(u16x8*)&Ahl[dst] = oh;
        *(u16x8*)&All[dst] = ol;
      }
      __syncthreads();
#pragma unroll
      for (int kk = 0; kk < 2; ++kk) {
        const int pb = ((kk * 4 + g) ^ x7) * 8;
        u16x8 bh = ld8(&Bhl[(w * 16 + ln) * 64 + pb]);
        u16x8 bl = ld8(&Bll[(w * 16 + ln) * 64 + pb]);
#pragma unroll
        for (int mi = 0; mi < 4; ++mi) {
          u16x8 ah = ld8(&Ahl[(mi * 16 + ln) * 64 + pb]);
          u16x8 al = ld8(&All[(mi * 16 + ln) * 64 + pb]);
          acc[mi] = MFMA(ah, bh, acc[mi]);
          acc[mi] = MFMA(ah, bl, acc[mi]);
          acc[mi] = MFMA(al, bh, acc[mi]);
        }
      }
      __syncthreads();
    }
#pragma unroll
    for (int mi = 0; mi < 4; ++mi) {
      const int col = n0 + w * 16 + ln;
#pragma unroll
      for (int pp = 0; pp < 4; ++pp) {
        const int row = m0 + mi * 16 + g * 4 + pp;
        const float val = acc[mi][pp];
        unsigned short hi = f2bf(val);
        Ch[(size_t)row * H + col] = hi;
        Cl[(size_t)row * H + col] = f2bf(val - bf2f(hi));
      }
    }
    return;
  }

  // --------- RsW 128x128 (round-14 form); out row = d*32+z -----------------
  unsigned short* Asl0 = LDS;           // 16 KB
  unsigned short* Asl1 = LDS + 8192;    // 16 KB (A double buffer)
  unsigned short* Bsl = LDS + 16384;    // 16 KB
  const int rid = wg - 432;                        // 0..1151; rid&7 == wg&7
  const int nb = (rid & 7) * 144 + (rid >> 3);     // chunked XCD swizzle
  const int z = nb / 36, t5 = nb - z * 36;
  const int d0 = (t5 / 6) * 128, k0 = (t5 % 6) * 128;
  const int wr = w >> 1, wc = w & 1;
  const unsigned short* Ag = Wm1bf + (size_t)(d0 + srow) * H + skb;
  const float* Bg = ((z < 16) ? Rsf : Rdf) + (size_t)(z & 15) * (H * H);
  const int kb8 = tid & 7, rb = tid >> 3;
  const float* Bq = Bg + (size_t)(k0 + rb) * H + kb8 * 8;
  const int bdst = rb * 64 + (kb8 ^ (rb & 7)) * 8;

#define LOADB_(kbv, Ra, Rb)                                  \
  _Pragma("unroll") for (int q = 0; q < 4; ++q) {            \
    const float* s_ = Bq + (size_t)(q * 32) * H + (kbv);     \
    Ra[q] = *(const float4*)s_;                              \
    Rb[q] = *(const float4*)(s_ + 4);                        \
  }
#define WRITEB_(Ra, Rb)                                      \
  _Pragma("unroll") for (int q = 0; q < 4; ++q) {            \
    u16x8 o_; unsigned int* po_ = (unsigned int*)&o_;        \
    po_[0] = cvtpk(Ra[q].x, Ra[q].y);                        \
    po_[1] = cvtpk(Ra[q].z, Ra[q].w);                        \
    po_[2] = cvtpk(Rb[q].x, Rb[q].y);                        \
    po_[3] = cvtpk(Rb[q].z, Rb[q].w);                        \
    *(u16x8*)&Bsl[q * 2048 + bdst] = o_;                     \
  }
#define GLDSA_(kbv, buf)                                     \
  _Pragma("unroll") for (int c4 = 0; c4 < 4; ++c4) {         \
    const int c_ = w * 4 + c4;                               \
    GLDS16(Ag + (size_t)(c_ * 8) * H + (kbv), &(buf)[c_ * 512]); \
  }

  f32x4 acc[4][4];
#pragma unroll
  for (int mi = 0; mi < 4; ++mi)
#pragma unroll
    for (int ni = 0; ni < 4; ++ni) acc[mi][ni] = (f32x4){0.f, 0.f, 0.f, 0.f};
  float4 ra[4], rbv[4];
  GLDSA_(0, Asl0);
  LOADB_(0, ra, rbv);
  WRITEB_(ra, rbv);
  __syncthreads();
#pragma unroll
  for (int t = 0; t < 12; ++t) {
    unsigned short* Acur = (t & 1) ? Asl1 : Asl0;
    unsigned short* Anxt = (t & 1) ? Asl0 : Asl1;
    if (t < 11) {
      GLDSA_((t + 1) * 64, Anxt);      // A(t+1) -> other buffer, issued early
      LOADB_((t + 1) * 64, ra, rbv);   // B(t+1) -> regs, issued early
    }
    __builtin_amdgcn_sched_barrier(0); // pin issues above the MFMA block
#pragma unroll
    for (int kk = 0; kk < 2; ++kk) {
      u16x8 af[4], bf[4];
      const int pb = ((kk * 4 + g) ^ x7) * 8;
#pragma unroll
      for (int mi = 0; mi < 4; ++mi) af[mi] = ld8(&Acur[(wr * 64 + mi * 16 + ln) * 64 + pb]);
#pragma unroll
      for (int ni = 0; ni < 4; ++ni) bf[ni] = ld8(&Bsl[(wc * 64 + ni * 16 + ln) * 64 + pb]);
#pragma unroll
      for (int mi = 0; mi < 4; ++mi)
#pragma unroll
        for (int ni = 0; ni < 4; ++ni) acc[mi][ni] = MFMA(af[mi], bf[ni], acc[mi][ni]);
    }
    __syncthreads();                   // drains A(t+1)/B(t+1); compute hid most
    if (t < 11) {
      WRITEB_(ra, rbv);                // B regs ready; cvt+ds_write
      __syncthreads();                 // cheap: no outstanding VMEM
    }
  }
#pragma unroll
  for (int mi = 0; mi < 4; ++mi) {
    const int d = d0 + wr * 64 + mi * 16 + g * 4;
#pragma unroll
    for (int ni = 0; ni < 4; ++ni) {
      const int k = k0 + wc * 64 + ni * 16 + ln;
      unsigned short* o = RsWt + ((size_t)d * 32 + z) * H + k;
#pragma unroll
      for (int pp = 0; pp < 4; ++pp) o[(size_t)pp * 32 * H] = f2bf(acc[mi][ni][pp]);
    }
  }
#undef LOADB_
#undef WRITEB_
#undef GLDSA_
}

// ---------------- K-split(4) hilo GEMM for gx (no bias, raw partials) -------
__global__ __launch_bounds__(256) void k_btks(
    const unsigned short* __restrict__ Ahi, const unsigned short* __restrict__ Alo,
    const unsigned short* __restrict__ Bhi, const unsigned short* __restrict__ Blo,
    float* __restrict__ Cp) {
  const int tid = threadIdx.x;
  const int w = tid >> 6, l = tid & 63, g = l >> 4, ln = l & 15;
  const int m0 = blockIdx.y * 64 + w * 16;
  const int n0 = blockIdx.x * 64;
  const int kh = blockIdx.z, kb0 = kh * 192;
  const unsigned short* aph = Ahi + (size_t)(m0 + ln) * H + kb0 + g * 8;
  const unsigned short* apl = Alo + (size_t)(m0 + ln) * H + kb0 + g * 8;
  const unsigned short* bph[4];
  const unsigned short* bpl[4];
#pragma unroll
  for (int nt = 0; nt < 4; ++nt) {
    bph[nt] = Bhi + (size_t)(n0 + nt * 16 + ln) * H + kb0 + g * 8;
    bpl[nt] = Blo + (size_t)(n0 + nt * 16 + ln) * H + kb0 + g * 8;
  }
  f32x4 acc[4];
#pragma unroll
  for (int nt = 0; nt < 4; ++nt) acc[nt] = (f32x4){0.f, 0.f, 0.f, 0.f};
  u16x8 ah[2], al[2], bh[2][4], bl[2][4];
  ah[0] = ld8(aph);
  al[0] = ld8(apl);
#pragma unroll
  for (int nt = 0; nt < 4; ++nt) { bh[0][nt] = ld8(bph[nt]); bl[0][nt] = ld8(bpl[nt]); }
#pragma unroll
  for (int t = 0; t < 6; ++t) {
    const int cur = t & 1, nxt = cur ^ 1;
    if (t < 5) {
      const int ko = (t + 1) * 32;
      ah[nxt] = ld8(aph + ko);
      al[nxt] = ld8(apl + ko);
#pragma unroll
      for (int nt = 0; nt < 4; ++nt) {
        bh[nxt][nt] = ld8(bph[nt] + ko);
        bl[nxt][nt] = ld8(bpl[nt] + ko);
      }
    }
#pragma unroll
    for (int nt = 0; nt < 4; ++nt) {
      acc[nt] = MFMA(ah[cur], bh[cur][nt], acc[nt]);
      acc[nt] = MFMA(ah[cur], bl[cur][nt], acc[nt]);
      acc[nt] = MFMA(al[cur], bh[cur][nt], acc[nt]);
    }
  }
#pragma unroll
  for (int nt = 0; nt < 4; ++nt) {
    const int col = n0 + nt * 16 + ln;
#pragma unroll
    for (int pp = 0; pp < 4; ++pp) {
      const int row = m0 + g * 4 + pp;
      Cp[(size_t)kh * (NTOT * GW) + (size_t)row * GW + col] = acc[nt][pp];
    }
  }
}

// ---------------- per-step LDS-staged tiled GEMM: gh | A4 | twB -------------
// 64(M) x 128(N) tiles, BK=64. Bijective XCD swizzle.
// Paths 1/2: A+B double-buffered, early issue. Path 0 (gh, hilo): original.
__global__ __launch_bounds__(256) void k_tile(
    const unsigned short* __restrict__ hhi, const unsigned short* __restrict__ hlo,
    const unsigned short* __restrict__ W1cat, const float* __restrict__ b1cat,
    const unsigned short* __restrict__ Whhh, const unsigned short* __restrict__ Whhl,
    const float* __restrict__ bhh, const unsigned short* __restrict__ RsWt,
    float* __restrict__ A4, float* __restrict__ ghb, unsigned short* __restrict__ twB) {
  __shared__ unsigned short LDS[24576];  // 48 KB
  const int orig = blockIdx.x;           // 702 blocks
  const int qq = 87, rr = 6;             // 702 = 8*87 + 6
  const int xcd = orig & 7, idx = orig >> 3;
  const int bid = (xcd < rr ? xcd * (qq + 1) : rr * (qq + 1) + (xcd - rr) * qq) + idx;
  const int tid = threadIdx.x, w = tid >> 6, l = tid & 63, g = l >> 4, ln = l & 15;
  int path, m, n;
  if (bid < 54)       { path = 0; n = bid / 3;         m = bid % 3; }
  else if (bid < 126) { path = 1; n = (bid - 54) / 3;  m = (bid - 54) % 3; }
  else                { path = 2; n = (bid - 126) / 3; m = (bid - 126) % 3; }
  const int m0 = m * 64, n0 = n * 128;
  const int srow = l >> 3;
  const int skb = ((l & 7) ^ srow) * 8;
  const int x7 = ln & 7;
  f32x4 acc[4][2];
#pragma unroll
  for (int mi = 0; mi < 4; ++mi)
#pragma unroll
    for (int ni = 0; ni < 2; ++ni) acc[mi][ni] = (f32x4){0.f, 0.f, 0.f, 0.f};

  if (path == 0) {
    unsigned short* Ah = LDS;
    unsigned short* Al = LDS + 4096;
    unsigned short* Bh = LDS + 8192;
    unsigned short* Bl = LDS + 16384;
    const unsigned short* Agh = hhi + (size_t)(m0 + srow) * H + skb;
    const unsigned short* Agl = hlo + (size_t)(m0 + srow) * H + skb;
    const unsigned short* Bgh = Whhh + (size_t)(n0 + srow) * H + skb;
    const unsigned short* Bgl = Whhl + (size_t)(n0 + srow) * H + skb;
    for (int kb = 0; kb < H; kb += 64) {
#pragma unroll
      for (int c2 = 0; c2 < 2; ++c2) {
        const int c = w * 2 + c2;
        GLDS16(Agh + (size_t)(c * 8) * H + kb, &Ah[c * 512]);
        GLDS16(Agl + (size_t)(c * 8) * H + kb, &Al[c * 512]);
      }
#pragma unroll
      for (int c4 = 0; c4 < 4; ++c4) {
        const int c = w * 4 + c4;
        GLDS16(Bgh + (size_t)(c * 8) * H + kb, &Bh[c * 512]);
        GLDS16(Bgl + (size_t)(c * 8) * H + kb, &Bl[c * 512]);
      }
      __syncthreads();
#pragma unroll
      for (int kk = 0; kk < 2; ++kk) {
        const int pb = ((kk * 4 + g) ^ x7) * 8;
        u16x8 af[4], bf[2], alf[4], blf[2];
#pragma unroll
        for (int mi = 0; mi < 4; ++mi) {
          af[mi] = ld8(&Ah[(mi * 16 + ln) * 64 + pb]);
          alf[mi] = ld8(&Al[(mi * 16 + ln) * 64 + pb]);
        }
#pragma unroll
        for (int ni = 0; ni < 2; ++ni) {
          bf[ni] = ld8(&Bh[(w * 32 + ni * 16 + ln) * 64 + pb]);
          blf[ni] = ld8(&Bl[(w * 32 + ni * 16 + ln) * 64 + pb]);
        }
#pragma unroll
        for (int mi = 0; mi < 4; ++mi)
#pragma unroll
          for (int ni = 0; ni < 2; ++ni) {
            acc[mi][ni] = MFMA(af[mi], bf[ni], acc[mi][ni]);
            acc[mi][ni] = MFMA(af[mi], blf[ni], acc[mi][ni]);
            acc[mi][ni] = MFMA(alf[mi], bf[ni], acc[mi][ni]);
          }
      }
      __syncthreads();
    }
#pragma unroll
    for (int mi = 0; mi < 4; ++mi)
#pragma unroll
      for (int ni = 0; ni < 2; ++ni) {
        const int col = n0 + w * 32 + ni * 16 + ln;
        const float bv = bhh[col];
#pragma unroll
        for (int pp = 0; pp < 4; ++pp) {
          const int row = m0 + mi * 16 + g * 4 + pp;
          ghb[(size_t)row * GW + col] = acc[mi][ni][pp] + bv;
        }
      }
    return;
  }

  unsigned short* As0 = LDS;            // 8 KB (64x64)
  unsigned short* As1 = LDS + 4096;
  unsigned short* Bs0 = LDS + 8192;     // 16 KB (128x64)
  unsigned short* Bs1 = LDS + 16384;
  const unsigned short* Bsrc = (path == 1) ? W1cat : RsWt;
  const unsigned short* Agh = hhi + (size_t)(m0 + srow) * H + skb;
  const unsigned short* Bgh = Bsrc + (size_t)(n0 + srow) * H + skb;

#define GLDSA2_(kbv, buf)                                    \
  _Pragma("unroll") for (int c2 = 0; c2 < 2; ++c2) {         \
    const int c_ = w * 2 + c2;                               \
    GLDS16(Agh + (size_t)(c_ * 8) * H + (kbv), &(buf)[c_ * 512]); \
  }
#define GLDSB2_(kbv, buf)                                    \
  _Pragma("unroll") for (int c4 = 0; c4 < 4; ++c4) {         \
    const int c_ = w * 4 + c4;                               \
    GLDS16(Bgh + (size_t)(c_ * 8) * H + (kbv), &(buf)[c_ * 512]); \
  }

  GLDSA2_(0, As0);
  GLDSB2_(0, Bs0);
  __syncthreads();
#pragma unroll
  for (int t = 0; t < 12; ++t) {
    unsigned short* Acur = (t & 1) ? As1 : As0;
    unsigned short* Bcur = (t & 1) ? Bs1 : Bs0;
    unsigned short* Anxt = (t & 1) ? As0 : As1;
    unsigned short* Bnxt = (t & 1) ? Bs0 : Bs1;
    if (t < 11) {
      GLDSA2_((t + 1) * 64, Anxt);
      GLDSB2_((t + 1) * 64, Bnxt);
    }
    __builtin_amdgcn_sched_barrier(0);
#pragma unroll
    for (int kk = 0; kk < 2; ++kk) {
      const int pb = ((kk * 4 + g) ^ x7) * 8;
      u16x8 af[4], bf[2];
#pragma unroll
      for (int mi = 0; mi < 4; ++mi) af[mi] = ld8(&Acur[(mi * 16 + ln) * 64 + pb]);
#pragma unroll
      for (int ni = 0; ni < 2; ++ni) bf[ni] = ld8(&Bcur[(w * 32 + ni * 16 + ln) * 64 + pb]);
#pragma unroll
      for (int mi = 0; mi < 4; ++mi)
#pragma unroll
        for (int ni = 0; ni < 2; ++ni) acc[mi][ni] = MFMA(af[mi], bf[ni], acc[mi][ni]);
    }
    __syncthreads();
  }
#undef GLDSA2_
#undef GLDSB2_

  if (path == 2) {
#pragma unroll
    for (int mi = 0; mi < 4; ++mi)
#pragma unroll
      for (int ni = 0; ni < 2; ++ni) {
        const int c = n0 + w * 32 + ni * 16 + ln;
#pragma unroll
        for (int pp = 0; pp < 4; ++pp) {
          const int j = m0 + mi * 16 + g * 4 + pp;
          twB[(size_t)j * 24576 + c] = f2bf(acc[mi][ni][pp]);
        }
      }
  } else {
#pragma unroll
    for (int mi = 0; mi < 4; ++mi)
#pragma unroll
      for (int ni = 0; ni < 2; ++ni) {
        const int col = n0 + w * 32 + ni * 16 + ln;
        const float bv = b1cat[col];
#pragma unroll
        for (int pp = 0; pp < 4; ++pp) {
          const int row = m0 + mi * 16 + g * 4 + pp;
          A4[(size_t)row * A4W + col] = acc[mi][ni][pp] + bv;
        }
      }
  }
}

// ---------------- pair logits + softmax -> swA[j][i][32] (bf16) -------------
__global__ __launch_bounds__(256) void k_pairlog(
    const float* __restrict__ A4, const unsigned short* __restrict__ W2sbf,
    const unsigned short* __restrict__ W2dbf, const float* __restrict__ b2s,
    const float* __restrict__ b2d, unsigned short* __restrict__ swA) {
  __shared__ float red[8][16][17];
  const int i = blockIdx.x, jb = blockIdx.y;
  const int tid = threadIdx.x, w = tid >> 6, l = tid & 63;
  const int g = l >> 4, ln = l & 15;
  const int j = jb * 16 + ln;
  const float* BsP = A4 + (size_t)j * A4W + 768 + g * 8;
  const float* BdP = A4 + (size_t)j * A4W + 2304 + g * 8;
  const float* AsP = A4 + (size_t)i * A4W + g * 8;
  const float* AdP = A4 + (size_t)i * A4W + 1536 + g * 8;
  const unsigned short* WsP = W2sbf + (size_t)ln * H + g * 8;
  const unsigned short* WdP = W2dbf + (size_t)ln * H + g * 8;
  f32x4 accs = (f32x4){0.f, 0.f, 0.f, 0.f}, accd = (f32x4){0.f, 0.f, 0.f, 0.f};
#pragma unroll
  for (int tt = 0; tt < 6; ++tt) {
    const int ko = (w * 6 + tt) * 32;
    float4 b0 = *(const float4*)(BsP + ko), b1 = *(const float4*)(BsP + ko + 4);
    float4 a0 = *(const float4*)(AsP + ko), a1 = *(const float4*)(AsP + ko + 4);
    float4 e0 = *(const float4*)(BdP + ko), e1 = *(const float4*)(BdP + ko + 4);
    float4 c0 = *(const float4*)(AdP + ko), c1 = *(const float4*)(AdP + ko + 4);
    u16x8 afs, afd;
    unsigned int* ps = (unsigned int*)&afs;
    ps[0] = cvtpk(relu(a0.x + b0.x), relu(a0.y + b0.y));
    ps[1] = cvtpk(relu(a0.z + b0.z), relu(a0.w + b0.w));
    ps[2] = cvtpk(relu(a1.x + b1.x), relu(a1.y + b1.y));
    ps[3] = cvtpk(relu(a1.z + b1.z), relu(a1.w + b1.w));
    unsigned int* pd = (unsigned int*)&afd;
    pd[0] = cvtpk(relu(c0.x + e0.x), relu(c0.y + e0.y));
    pd[1] = cvtpk(relu(c0.z + e0.z), relu(c0.w + e0.w));
    pd[2] = cvtpk(relu(c1.x + e1.x), relu(c1.y + e1.y));
    pd[3] = cvtpk(relu(c1.z + e1.z), relu(c1.w + e1.w));
    accs = MFMA(afs, ld8(WsP + ko), accs);
    accd = MFMA(afd, ld8(WdP + ko), accd);
  }
#pragma unroll
  for (int pp = 0; pp < 4; ++pp) {
    red[w * 2][g * 4 + pp][ln] = accs[pp];
    red[w * 2 + 1][g * 4 + pp][ln] = accd[pp];
  }
  __syncthreads();
  const int j2 = tid >> 4, r = tid & 15;
  float vs = red[0][j2][r] + red[2][j2][r] + red[4][j2][r] + red[6][j2][r] + b2s[r];
  float vd = red[1][j2][r] + red[3][j2][r] + red[5][j2][r] + red[7][j2][r] + b2d[r];
  float ms = vs;
  ms = fmaxf(ms, __shfl_xor(ms, 1)); ms = fmaxf(ms, __shfl_xor(ms, 2));
  ms = fmaxf(ms, __shfl_xor(ms, 4)); ms = fmaxf(ms, __shfl_xor(ms, 8));
  float md = vd;
  md = fmaxf(md, __shfl_xor(md, 1)); md = fmaxf(md, __shfl_xor(md, 2));
  md = fmaxf(md, __shfl_xor(md, 4)); md = fmaxf(md, __shfl_xor(md, 8));
  float es = __expf(vs - ms), ed = __expf(vd - md);
  float ss = es;
  ss += __shfl_xor(ss, 1); ss += __shfl_xor(ss, 2); ss += __shfl_xor(ss, 4); ss += __shfl_xor(ss, 8);
  float sd = ed;
  sd += __shfl_xor(sd, 1); sd += __shfl_xor(sd, 2); sd += __shfl_xor(sd, 4); sd += __shfl_xor(sd, 8);
  const size_t o = (size_t)(jb * 16 + j2) * 6144 + (size_t)i * 32;
  swA[o + r] = f2bf(es / ss);
  swA[o + 16 + r] = f2bf(ed / sd);
}

// ---------------- per-pair weighted message + relu + sum_j -> v_part --------
// js in [0,16): 12 j each. Grid (12,3,16) = 576 blocks.
__global__ __launch_bounds__(256) void k_pairmsg(const unsigned short* __restrict__ swA,
                                                 const unsigned short* __restrict__ twB,
                                                 const float* __restrict__ bm1,
                                                 float* __restrict__ vpart) {
  const int dt = blockIdx.x, it = blockIdx.y, js = blockIdx.z;
  const int tid = threadIdx.x;
  const int w = tid >> 6, l = tid & 63, g = l >> 4, ln = l & 15;
  const int i0 = it * 64 + w * 16;
  const int d0 = dt * 64;
  float bm1v[4];
#pragma unroll
  for (int nt = 0; nt < 4; ++nt) bm1v[nt] = bm1[d0 + nt * 16 + ln];
  f32x4 vacc[4];
#pragma unroll
  for (int nt = 0; nt < 4; ++nt) vacc[nt] = (f32x4){0.f, 0.f, 0.f, 0.f};
  const unsigned short* ap = swA + (size_t)(i0 + ln) * 32 + g * 8 + (size_t)js * 12 * 6144;
  const unsigned short* bp[4];
#pragma unroll
  for (int nt = 0; nt < 4; ++nt)
    bp[nt] = twB + (size_t)(d0 + nt * 16 + ln) * 32 + g * 8 + (size_t)js * 12 * 24576;
  const f32x4 z4 = (f32x4){0.f, 0.f, 0.f, 0.f};
#pragma unroll 4
  for (int jj = 0; jj < 12; ++jj) {
    u16x8 a = ld8(ap + (size_t)jj * 6144);
#pragma unroll
    for (int nt = 0; nt < 4; ++nt) {
      u16x8 b = ld8(bp[nt] + (size_t)jj * 24576);
      f32x4 mf = MFMA(a, b, z4);
#pragma unroll
      for (int pp = 0; pp < 4; ++pp) vacc[nt][pp] += fmaxf(mf[pp] + bm1v[nt], 0.f);
    }
  }
#pragma unroll
  for (int nt = 0; nt < 4; ++nt)
#pragma unroll
    for (int pp = 0; pp < 4; ++pp) {
      const int row = i0 + g * 4 + pp;
      vpart[(size_t)js * 147456 + (size_t)row * H + d0 + nt * 16 + ln] = vacc[nt][pp];
    }
}

__global__ void k_vred(const float* __restrict__ vpart, unsigned short* __restrict__ vhi,
                       unsigned short* __restrict__ vlo) {
  int e = blockIdx.x * 256 + threadIdx.x;  // 147456
  float s = 0.f;
#pragma unroll
  for (int q = 0; q < 16; ++q) s += vpart[(size_t)q * 147456 + e];
  s *= (1.0f / 192.0f);
  unsigned short hi = f2bf(s);
  vhi[e] = hi;
  vlo[e] = f2bf(s - bf2f(hi));
}

__global__ void k_gru(const float* __restrict__ gxp, const float* __restrict__ bcv,
                      const float* __restrict__ gh, float* __restrict__ h,
                      unsigned short* __restrict__ hhi, unsigned short* __restrict__ hlo,
                      float* __restrict__ out, int last) {
  int e = blockIdx.x * 256 + threadIdx.x;  // 147456
  int i = e / H, k = e - i * H;
  size_t base = (size_t)i * GW;
  const size_t S = (size_t)NTOT * GW;
  float rr = gxp[base + k] + gxp[S + base + k] + gxp[2 * S + base + k] +
             gxp[3 * S + base + k] + bcv[k] + gh[base + k];
  float zz = gxp[base + H + k] + gxp[S + base + H + k] + gxp[2 * S + base + H + k] +
             gxp[3 * S + base + H + k] + bcv[H + k] + gh[base + H + k];
  float r = 1.f / (1.f + __expf(-rr));
  float z = 1.f / (1.f + __expf(-zz));
  float nn = gxp[base + 2 * H + k] + gxp[S + base + 2 * H + k] +
             gxp[2 * S + base + 2 * H + k] + gxp[3 * S + base + 2 * H + k] +
             bcv[2 * H + k];
  float n = tanhf(nn + r * gh[base + 2 * H + k]);
  float hv = (1.f - z) * n + z * h[e];
  h[e] = hv;
  unsigned short hi = f2bf(hv);
  hhi[e] = hi;
  hlo[e] = f2bf(hv - bf2f(hi));
  if (last && i >= 64) out[(size_t)(i - 64) * H + k] = hv;
}

// ---------------- launch ----------------------------------------------------

extern "C" void kernel_launch(void* const* d_in, const int* in_sizes, int n_in,
                              void* d_out, int out_size, void* d_ws, size_t ws_size,
                              hipStream_t stream) {
  const float* asp = (const float*)d_in[0];
  const float* qry = (const float*)d_in[1];
  const float* W1s = (const float*)d_in[3];
  const float* b1s = (const float*)d_in[4];
  const float* W2s = (const float*)d_in[5];
  const float* b2s = (const float*)d_in[6];
  const float* W1d = (const float*)d_in[7];
  const float* b1d = (const float*)d_in[8];
  const float* W2d = (const float*)d_in[9];
  const float* b2d = (const float*)d_in[10];
  const float* Rs  = (const float*)d_in[11];
  const float* Rd  = (const float*)d_in[12];
  const float* Wm1 = (const float*)d_in[13];
  const float* bm1 = (const float*)d_in[14];
  const float* Wm2 = (const float*)d_in[15];
  const float* bm2 = (const float*)d_in[16];
  const float* Wih = (const float*)d_in[17];
  const float* Whh = (const float*)d_in[18];
  const float* bih = (const float*)d_in[19];
  const float* bhh = (const float*)d_in[20];
  float* out = (float*)d_out;

  char* p = (char*)d_ws;
  auto take = [&](size_t bytes) {
    char* q = p;
    p += (bytes + 255) & ~(size_t)255;
    return q;
  };
  // ---- step-scratch region, aliased during prep ----
  float* h            = (float*)take((size_t)NTOT * H * 4);
  unsigned short* hhi = (unsigned short*)take((size_t)NTOT * H * 2);
  unsigned short* hlo = (unsigned short*)take((size_t)NTOT * H * 2);
  float* A4           = (float*)take((size_t)NTOT * A4W * 4);
  float* ghb          = (float*)take((size_t)NTOT * GW * 4);
  unsigned short* vhi = (unsigned short*)take((size_t)NTOT * H * 2);
  unsigned short* vlo = (unsigned short*)take((size_t)NTOT * H * 2);
  float* vpart        = (float*)take((size_t)16 * NTOT * H * 4);
  unsigned short* swA = (unsigned short*)take((size_t)NTOT * NTOT * 32 * 2);
  unsigned short* twB = (unsigned short*)take((size_t)NTOT * H * 32 * 2);  // also gx partials
  // ---- permanent weights ----
  unsigned short* RsWt = (unsigned short*)take((size_t)2 * 16 * H * H * 2);
  unsigned short* Wm1bf = (unsigned short*)take((size_t)H * H * 2);
  unsigned short* W2sbf = (unsigned short*)take((size_t)16 * H * 2);
  unsigned short* W2dbf = (unsigned short*)take((size_t)16 * H * 2);
  unsigned short* W1cat = (unsigned short*)take((size_t)A4W * H * 2);
  float* b1cat        = (float*)take((size_t)A4W * 4);
  unsigned short* Whhh = (unsigned short*)take((size_t)GW * H * 2);
  unsigned short* Whhl = (unsigned short*)take((size_t)GW * H * 2);
  unsigned short* Wch  = (unsigned short*)take((size_t)GW * H * 2);
  unsigned short* Wcl  = (unsigned short*)take((size_t)GW * H * 2);
  float* bc           = (float*)take((size_t)GW * 4);
  // ---- prep-phase aliases (within step-scratch, after h/hhi/hlo @1,179,648) ----
  unsigned short* Wm2th = (unsigned short*)((char*)d_ws + 1179648);
  unsigned short* Wm2tl = Wm2th + (size_t)H * H;  // ends ~3.54 MB

  // ---- once-per-launch prep ----
  k_prep<<<5928, 256, 0, stream>>>(Wm1, W2s, W2d, Whh, Wih, Wm2, W1s, W1d, b1s, b1d,
                                   bm2, bih, asp, qry,
                                   Wm1bf, W2sbf, W2dbf, Whhh, Whhl,
                                   Wm2th, Wm2tl, W1cat, b1cat, bc, h, hhi, hlo);
  k_pre2<<<1584, 256, 0, stream>>>(Wm1bf, Rs, Rd, RsWt, Wih, Wm2th, Wm2tl, Wch, Wcl);

  // ---- propagation steps ----
  for (int step = 0; step < 3; ++step) {
    k_tile<<<702, 256, 0, stream>>>(hhi, hlo, W1cat, b1cat, Whhh, Whhl, bhh, RsWt,
                                    A4, ghb, twB);
    k_pairlog<<<dim3(192, 12), 256, 0, stream>>>(A4, W2sbf, W2dbf, b2s, b2d, swA);
    k_pairmsg<<<dim3(12, 3, 16), 256, 0, stream>>>(swA, twB, bm1, vpart);
    k_vred<<<576, 256, 0, stream>>>(vpart, vhi, vlo);
    k_btks<<<dim3(36, 3, 4), 256, 0, stream>>>(vhi, vlo, Wch, Wcl, (float*)twB);
    k_gru<<<576, 256, 0, stream>>>((float*)twB, bc, ghb, h, hhi, hlo, out, step == 2);
  }
  (void)in_sizes; (void)n_in; (void)out_size; (void)ws_size;
}